// Round 7
// baseline (1896.876 us; speedup 1.0000x reference)
//
#include <hip/hip_runtime.h>
#include <hip/hip_bf16.h>

#define N_NODES 50000
#define NE      800000

typedef __attribute__((ext_vector_type(8))) unsigned short u16x8;

__device__ __forceinline__ float bf2f(unsigned short u) {
    union { unsigned int i; float f; } v; v.i = ((unsigned int)u) << 16; return v.f;
}
__device__ __forceinline__ unsigned short f2bf(float f) {
    union { unsigned int i; float f; } v; v.f = f;
    unsigned int x = v.i;
    return (unsigned short)((x + 0x7fffu + ((x >> 16) & 1u)) >> 16);  // RNE
}

// ---------------- GEMM + bias + row l2norm (VALU fp32) ----------------
// X fp32 [M][K] C-order, W fp32 [K][256] C-order, bias fp32[256] -> out FP32 [M][256] = l2norm(X@W+b)
__global__ __launch_bounds__(256) void k_gemm_norm(
    const float* __restrict__ X, const float* __restrict__ W,
    const float* __restrict__ bias, float* __restrict__ out, int M, int K)
{
    __shared__ float Xt[256][36];
    const int tid = threadIdx.x;
    const int m0 = blockIdx.x * 32;
    const int rg = tid >> 6, ct = tid & 63;

    float acc[8][4];
    for (int a = 0; a < 8; ++a) for (int b = 0; b < 4; ++b) acc[a][b] = 0.f;

    for (int kc = 0; kc < K; kc += 256) {
        __syncthreads();
        for (int p = 0; p < 8; ++p) {
            int idx = tid + p * 256;
            int r = idx >> 6, c4 = idx & 63;
            int row = m0 + r;
            float4 v = make_float4(0.f, 0.f, 0.f, 0.f);
            if (row < M) v = *(const float4*)(X + (size_t)row * K + kc + c4 * 4);
            Xt[c4 * 4 + 0][r] = v.x; Xt[c4 * 4 + 1][r] = v.y;
            Xt[c4 * 4 + 2][r] = v.z; Xt[c4 * 4 + 3][r] = v.w;
        }
        __syncthreads();
        for (int k = 0; k < 256; ++k) {
            float4 b4 = *(const float4*)(W + (size_t)(kc + k) * 256 + ct * 4);
            const float* ap = &Xt[k][rg * 8];
            float4 a0 = *(const float4*)ap;
            float4 a1 = *(const float4*)(ap + 4);
            float av[8] = {a0.x, a0.y, a0.z, a0.w, a1.x, a1.y, a1.z, a1.w};
            for (int a = 0; a < 8; ++a) {
                acc[a][0] += av[a] * b4.x; acc[a][1] += av[a] * b4.y;
                acc[a][2] += av[a] * b4.z; acc[a][3] += av[a] * b4.w;
            }
        }
    }

    float4 bj = *(const float4*)(bias + ct * 4);
    for (int a = 0; a < 8; ++a) {
        acc[a][0] += bj.x; acc[a][1] += bj.y; acc[a][2] += bj.z; acc[a][3] += bj.w;
        float s = acc[a][0]*acc[a][0] + acc[a][1]*acc[a][1]
                + acc[a][2]*acc[a][2] + acc[a][3]*acc[a][3];
        for (int m = 1; m < 64; m <<= 1) s += __shfl_xor(s, m);
        float sc = 1.0f / fmaxf(sqrtf(s), 1e-12f);
        int row = m0 + rg * 8 + a;
        if (row < M) {
            float4 o = make_float4(acc[a][0] * sc, acc[a][1] * sc, acc[a][2] * sc, acc[a][3] * sc);
            *(float4*)(out + (size_t)row * 256 + ct * 4) = o;
        }
    }
}

// ---------------- Gram: G[i][j] += sum_m Z[m][i]*Z[m][j]  (Z fp32 [M][256]) ----------------
__global__ __launch_bounds__(256) void k_gram(const float* __restrict__ Z,
                                              float* __restrict__ G, int M)
{
    __shared__ float Zc[64][256];
    const int tid = threadIdx.x;
    const int ib = blockIdx.x;
    const int rg = tid >> 6, ct = tid & 63;
    const int base0 = blockIdx.y * 2048;

    float acc[8][4];
    for (int a = 0; a < 8; ++a) for (int b = 0; b < 4; ++b) acc[a][b] = 0.f;

    for (int sc = 0; sc < 32; ++sc) {
        int base = base0 + sc * 64;
        __syncthreads();
        for (int p = 0; p < 16; ++p) {
            int idx = tid + p * 256;          // 4096 float4 = 64 rows x 64
            int k = idx >> 6, c4 = idx & 63;
            int row = base + k;
            float4 v = make_float4(0.f, 0.f, 0.f, 0.f);
            if (row < M) v = *(const float4*)(Z + (size_t)row * 256 + c4 * 4);
            *(float4*)&Zc[k][c4 * 4] = v;
        }
        __syncthreads();
        for (int k = 0; k < 64; ++k) {
            const float* zp = &Zc[k][ib * 32 + rg * 8];
            float4 a0 = *(const float4*)zp;
            float4 a1 = *(const float4*)(zp + 4);
            float4 zj = *(const float4*)&Zc[k][ct * 4];
            float av[8] = {a0.x, a0.y, a0.z, a0.w, a1.x, a1.y, a1.z, a1.w};
            for (int a = 0; a < 8; ++a) {
                acc[a][0] += av[a] * zj.x; acc[a][1] += av[a] * zj.y;
                acc[a][2] += av[a] * zj.z; acc[a][3] += av[a] * zj.w;
            }
        }
    }
    for (int a = 0; a < 8; ++a)
        for (int b = 0; b < 4; ++b)
            atomicAdd(&G[(ib * 32 + rg * 8 + a) * 256 + ct * 4 + b], acc[a][b]);
}

// ---------------- small 256x256 helpers ----------------
__global__ __launch_bounds__(256) void k_max(const float* __restrict__ G, float* __restrict__ gmax)
{
    float m = -1e30f;
    for (int i = threadIdx.x; i < 65536; i += 256) m = fmaxf(m, G[i]);
    for (int s = 1; s < 64; s <<= 1) m = fmaxf(m, __shfl_xor(m, s));
    __shared__ float wm[4];
    if ((threadIdx.x & 63) == 0) wm[threadIdx.x >> 6] = m;
    __syncthreads();
    if (threadIdx.x == 0) *gmax = fmaxf(fmaxf(wm[0], wm[1]), fmaxf(wm[2], wm[3]));
}

__global__ void k_exp(const float* __restrict__ G, const float* __restrict__ gmax, float* __restrict__ E)
{
    const float inv_sqrt_n = 4.4721359549995794e-3f;   // 1/sqrt(50000)
    int i = blockIdx.x * 256 + threadIdx.x;
    E[i] = expf((G[i] - *gmax) * inv_sqrt_n);
}

__global__ __launch_bounds__(256) void k_rowsum(const float* __restrict__ E, float* __restrict__ rs)
{
    int i = blockIdx.x;
    float v = E[i * 256 + threadIdx.x];
    for (int m = 1; m < 64; m <<= 1) v += __shfl_xor(v, m);
    __shared__ float wm[4];
    if ((threadIdx.x & 63) == 0) wm[threadIdx.x >> 6] = v;
    __syncthreads();
    if (threadIdx.x == 0) rs[i] = wm[0] + wm[1] + wm[2] + wm[3];
}

__global__ void k_colsum(const float* __restrict__ E, float* __restrict__ cs)
{
    int j = threadIdx.x;
    float a = 0.f;
    for (int i = 0; i < 256; ++i) a += E[i * 256 + j];
    cs[j] = a;
}

__global__ void k_smacc(const float* __restrict__ E, const float* __restrict__ rs,
                        const float* __restrict__ cs, float* __restrict__ SMh)
{
    int i = blockIdx.x, j = threadIdx.x;
    float v = E[i * 256 + j] * rsqrtf(rs[i] + 1e-10f) * rsqrtf(cs[j] + 1e-10f);
    SMh[i * 256 + j] += 0.25f * v;
}

__global__ void k_sinit(const float* __restrict__ SMh, float* __restrict__ S)
{
    int i = blockIdx.x, j = threadIdx.x;
    S[i * 256 + j] = SMh[i * 256 + j] + (i == j ? 1.0f : 0.0f);
}

__global__ __launch_bounds__(256) void k_sgemm(const float* __restrict__ P, const float* __restrict__ SMh,
                                               float* __restrict__ Pn, float* __restrict__ S)
{
    __shared__ float pr[256];
    int i = blockIdx.x, j = threadIdx.x;
    pr[j] = P[i * 256 + j];
    __syncthreads();
    float a = 0.f;
    for (int k = 0; k < 256; ++k) a += pr[k] * SMh[k * 256 + j];
    Pn[i * 256 + j] = a;
    S[i * 256 + j] += a;
}

// ---------------- ZM = 0.5*(ZM1+ZM2) from fp32 Z's: bf16 cur and bf16 PA ----------------
__global__ void k_zm(const float* __restrict__ z1, const float* __restrict__ z2,
                     unsigned short* __restrict__ C, unsigned short* __restrict__ PA)
{
    size_t i = ((size_t)blockIdx.x * 256 + threadIdx.x) * 4;
    float4 a = *(const float4*)(z1 + i);
    float4 b = *(const float4*)(z2 + i);
    ushort4 c;
    c.x = f2bf(0.5f * (a.x + b.x)); c.y = f2bf(0.5f * (a.y + b.y));
    c.z = f2bf(0.5f * (a.z + b.z)); c.w = f2bf(0.5f * (a.w + b.w));
    *(ushort4*)(C + i) = c;
    *(ushort4*)(PA + i) = c;
}

// ---------------- CSR build ----------------
__global__ void k_hist(const int* __restrict__ src, int* __restrict__ counts)
{
    int e = blockIdx.x * 256 + threadIdx.x;
    atomicAdd(&counts[src[e]], 1);
}

__global__ __launch_bounds__(256) void k_scan(const int* __restrict__ counts,
                                              int* __restrict__ rowptr, int* __restrict__ cursor)
{
    __shared__ int sums[256];
    int t = threadIdx.x;
    const int CH = 196;
    int lo = t * CH, hi = min(lo + CH, N_NODES);
    int s = 0;
    for (int i = lo; i < hi; ++i) s += counts[i];
    sums[t] = s;
    __syncthreads();
    if (t == 0) {
        int run = 0;
        for (int q = 0; q < 256; ++q) { int tmp = sums[q]; sums[q] = run; run += tmp; }
        rowptr[N_NODES] = run;
    }
    __syncthreads();
    int run = sums[t];
    for (int i = lo; i < hi; ++i) { rowptr[i] = run; cursor[i] = run; run += counts[i]; }
}

__global__ void k_scatter(const int* __restrict__ src, const int* __restrict__ dst,
                          const float* __restrict__ val, int* __restrict__ cursor,
                          int* __restrict__ sdst, float* __restrict__ sval)
{
    int e = blockIdx.x * 256 + threadIdx.x;
    int s = src[e];
    int pos = atomicAdd(&cursor[s], 1);
    sdst[pos] = dst[e];
    sval[pos] = val[e];
}

// ---------------- SpMM layer: nxt = 0.5 * A @ cur ; PA += nxt (bf16 state) ----------------
__global__ __launch_bounds__(256) void k_spmm(const int* __restrict__ rowptr, const int* __restrict__ sdst,
                                              const float* __restrict__ sval,
                                              const unsigned short* __restrict__ cur,
                                              unsigned short* __restrict__ nxt, unsigned short* __restrict__ PA)
{
    __shared__ int ed[256];
    __shared__ float ev[256];
    int i = blockIdx.x, j = threadIdx.x;
    int lo = rowptr[i], hi = rowptr[i + 1];
    float acc = 0.f;
    for (int base = lo; base < hi; base += 256) {
        int cnt = min(hi - base, 256);
        __syncthreads();
        if (j < cnt) { ed[j] = sdst[base + j]; ev[j] = sval[base + j]; }
        __syncthreads();
        for (int q = 0; q < cnt; ++q)
            acc += ev[q] * bf2f(cur[(size_t)ed[q] * 256 + j]);
    }
    float v = 0.5f * acc;
    size_t idx = (size_t)i * 256 + j;
    nxt[idx] = f2bf(v);
    PA[idx] = f2bf(bf2f(PA[idx]) + v);
}

// ---------------- HM = l2norm(PA @ S), PA bf16, out FP32 ----------------
__global__ __launch_bounds__(256) void k_hm(const unsigned short* __restrict__ PA, const float* __restrict__ S,
                                            float* __restrict__ out, int M)
{
    __shared__ float PAt[256][32];
    int tid = threadIdx.x;
    int m0 = blockIdx.x * 32;
    for (int p = 0; p < 4; ++p) {
        int idx = tid + p * 256;
        int r = idx >> 5, c8 = idx & 31;
        int row = m0 + r;
        u16x8 v = (u16x8)0;
        if (row < M) v = *(const u16x8*)(PA + (size_t)row * 256 + c8 * 8);
        for (int q = 0; q < 8; ++q) PAt[c8 * 8 + q][r] = bf2f(v[q]);
    }
    __syncthreads();
    int rg = tid >> 6;
    int ct = tid & 63;
    float acc[8][4];
    for (int a = 0; a < 8; ++a) for (int b = 0; b < 4; ++b) acc[a][b] = 0.f;
    for (int k = 0; k < 256; ++k) {
        float4 b4 = *(const float4*)(S + k * 256 + ct * 4);
        const float* ap = &PAt[k][rg * 8];
        float4 a0 = *(const float4*)(ap);
        float4 a1 = *(const float4*)(ap + 4);
        float av[8] = {a0.x, a0.y, a0.z, a0.w, a1.x, a1.y, a1.z, a1.w};
        for (int a = 0; a < 8; ++a) {
            acc[a][0] += av[a] * b4.x; acc[a][1] += av[a] * b4.y;
            acc[a][2] += av[a] * b4.z; acc[a][3] += av[a] * b4.w;
        }
    }
    for (int a = 0; a < 8; ++a) {
        float s = acc[a][0]*acc[a][0] + acc[a][1]*acc[a][1] + acc[a][2]*acc[a][2] + acc[a][3]*acc[a][3];
        for (int m = 1; m < 64; m <<= 1) s += __shfl_xor(s, m);
        float sc = 1.0f / fmaxf(sqrtf(s), 1e-12f);
        int row = m0 + rg * 8 + a;
        if (row < M) {
            float4 o = make_float4(acc[a][0] * sc, acc[a][1] * sc, acc[a][2] * sc, acc[a][3] * sc);
            *(float4*)(out + (size_t)row * 256 + ct * 4) = o;
        }
    }
}

// ---------------- diagnostic stamps (only fire on fatal host-visible anomalies) ----------------
__global__ void k_stamp(float* __restrict__ out, float c0, float c1, float c2)
{
    if (c0 != 0.f) out[0] = c0;
    if (c1 != 0.f) out[1] = c1;
    if (c2 != 0.f) out[2] = c2;
}

extern "C" void kernel_launch(void* const* d_in, const int* in_sizes, int n_in,
                              void* d_out, int out_size, void* d_ws, size_t ws_size,
                              hipStream_t stream)
{
    // inputs in setup_inputs() dict order; fp32 (confirmed R4), C-order as displayed.
    const float* X1   = (const float*)d_in[0];
    const float* X2   = (const float*)d_in[1];
    const int*   esrc = (const int*)d_in[2];
    const int*   edst = (const int*)d_in[3];
    const float* eval = (const float*)d_in[4];
    const float* W1   = (const float*)d_in[5];
    const float* b1   = (const float*)d_in[6];
    const float* W2   = (const float*)d_in[7];
    const float* b2   = (const float*)d_in[8];

    // d_out is FP32 (reference output dtype is float32; harness doc: "else float*")
    float* out_zm1 = (float*)d_out;
    float* out_zm2 = out_zm1 + (size_t)N_NODES * 256;
    float* out_hm  = out_zm2 + (size_t)N_NODES * 256;

    // ---- workspace carve (~59.8 MB) ----
    char* w = (char*)d_ws;
    unsigned short* PAb   = (unsigned short*)w; w += 25600000;
    unsigned short* curA  = (unsigned short*)w; w += 25600000;
    int* sdst             = (int*)w;            w += 3200000;
    float* sval           = (float*)w;          w += 3200000;
    int* counts           = (int*)w;            w += 200192;
    int* rowptr           = (int*)w;            w += 200192;
    int* cursor           = (int*)w;            w += 200192;
    float* G              = (float*)w;          w += 262144;
    float* Emat           = (float*)w;          w += 262144;
    float* SMh            = (float*)w;          w += 262144;
    float* S              = (float*)w;          w += 262144;
    float* P2             = (float*)w;          w += 262144;
    float* P3             = (float*)w;          w += 262144;
    float* rs             = (float*)w;          w += 1024;
    float* cs             = (float*)w;          w += 1024;
    float* gmax           = (float*)w;          w += 256;
    size_t ws_need = (size_t)(w - (char*)d_ws);

    // park bf16 ping buffer in the (fp32, 51.2MB) out_hm region — dead until k_hm
    unsigned short* curB  = (unsigned short*)out_hm;

    bool sizes_ok = (n_in == 9)
        && in_sizes[0] == 38400000 && in_sizes[1] == 25600000
        && in_sizes[2] == 800000 && in_sizes[3] == 800000 && in_sizes[4] == 800000
        && in_sizes[5] == 196608 && in_sizes[6] == 256
        && in_sizes[7] == 131072 && in_sizes[8] == 256;
    float c0 = (n_in != 9) ? 1000.f : 0.f;
    float c1 = (!sizes_ok && n_in == 9) ? 2000.f : 0.f;
    float c2 = (ws_size < ws_need) ? (4000.f + (float)(ws_size / 1000000ull)) : 0.f;

    // 1) ZM1/ZM2 (fp32 out)
    k_gemm_norm<<<(N_NODES + 31) / 32, 256, 0, stream>>>(X1, W1, b1, out_zm1, N_NODES, 768);
    k_gemm_norm<<<(N_NODES + 31) / 32, 256, 0, stream>>>(X2, W2, b2, out_zm2, N_NODES, 512);

    // 2) SMh = 0.25 * (ssoftmax(ZM1) + ssoftmax(ZM2))
    hipMemsetAsync(SMh, 0, 262144, stream);
    hipMemsetAsync(G, 0, 262144, stream);
    k_gram<<<dim3(8, 25), 256, 0, stream>>>(out_zm1, G, N_NODES);
    k_max<<<1, 256, 0, stream>>>(G, gmax);
    k_exp<<<256, 256, 0, stream>>>(G, gmax, Emat);
    k_rowsum<<<256, 256, 0, stream>>>(Emat, rs);
    k_colsum<<<1, 256, 0, stream>>>(Emat, cs);
    k_smacc<<<256, 256, 0, stream>>>(Emat, rs, cs, SMh);
    hipMemsetAsync(G, 0, 262144, stream);
    k_gram<<<dim3(8, 25), 256, 0, stream>>>(out_zm2, G, N_NODES);
    k_max<<<1, 256, 0, stream>>>(G, gmax);
    k_exp<<<256, 256, 0, stream>>>(G, gmax, Emat);
    k_rowsum<<<256, 256, 0, stream>>>(Emat, rs);
    k_colsum<<<1, 256, 0, stream>>>(Emat, cs);
    k_smacc<<<256, 256, 0, stream>>>(Emat, rs, cs, SMh);

    // 3) ZM -> curA (bf16), PAb (bf16)
    k_zm<<<12500, 256, 0, stream>>>(out_zm1, out_zm2, curA, PAb);

    // 4) CSR by src
    hipMemsetAsync(counts, 0, 200192, stream);
    k_hist<<<NE / 256, 256, 0, stream>>>(esrc, counts);
    k_scan<<<1, 256, 0, stream>>>(counts, rowptr, cursor);
    k_scatter<<<NE / 256, 256, 0, stream>>>(esrc, edst, eval, cursor, sdst, sval);

    // 5) 4 propagation layers (curB parked in out_hm region)
    k_spmm<<<N_NODES, 256, 0, stream>>>(rowptr, sdst, sval, curA, curB, PAb);
    k_spmm<<<N_NODES, 256, 0, stream>>>(rowptr, sdst, sval, curB, curA, PAb);
    k_spmm<<<N_NODES, 256, 0, stream>>>(rowptr, sdst, sval, curA, curB, PAb);
    k_spmm<<<N_NODES, 256, 0, stream>>>(rowptr, sdst, sval, curB, curA, PAb);

    // 6) S = I + B + B^2 + B^3   (B = 0.5*SM folded into SMh)
    k_sinit<<<256, 256, 0, stream>>>(SMh, S);
    k_sgemm<<<256, 256, 0, stream>>>(SMh, SMh, P2, S);
    k_sgemm<<<256, 256, 0, stream>>>(P2, SMh, P3, S);

    // 7) HM = l2norm(PA @ S) -> fp32 out (overwrites curB region — dead by now)
    k_hm<<<(N_NODES + 31) / 32, 256, 0, stream>>>(PAb, S, out_hm, N_NODES);

    // 8) diagnostic stamps (no-op when healthy)
    k_stamp<<<1, 1, 0, stream>>>(out_zm1, c0, c1, c2);
}

// Round 8
// 1307.016 us; speedup vs baseline: 1.4513x; 1.4513x over previous
//
#include <hip/hip_runtime.h>
#include <hip/hip_bf16.h>

#define N_NODES 50000
#define NE      800000

typedef __attribute__((ext_vector_type(4))) float f32x4;
typedef __attribute__((ext_vector_type(8))) short s16x8;
typedef __attribute__((ext_vector_type(8))) unsigned short u16x8;

__device__ __forceinline__ float bf2f(unsigned short u) {
    union { unsigned int i; float f; } v; v.i = ((unsigned int)u) << 16; return v.f;
}
__device__ __forceinline__ unsigned short f2bf(float f) {
    union { unsigned int i; float f; } v; v.f = f;
    unsigned int x = v.i;
    return (unsigned short)((x + 0x7fffu + ((x >> 16) & 1u)) >> 16);  // RNE
}

// ---------------- weights: W fp32 (K,256) C-order -> Wt bf16 [256][K] ----------------
__global__ void k_wt(const float* __restrict__ W, unsigned short* __restrict__ Wt, int K)
{
    int idx = blockIdx.x * 256 + threadIdx.x;          // = j*K + k
    int j = idx / K, k = idx - j * K;
    Wt[idx] = f2bf(W[(size_t)k * 256 + j]);
}

// ---------------- S fp32 [256][256] -> St bf16 transposed: St[j][k] = S[k][j] ----------------
__global__ void k_st(const float* __restrict__ S, unsigned short* __restrict__ St)
{
    int k = blockIdx.x, j = threadIdx.x;
    St[j * 256 + k] = f2bf(S[k * 256 + j]);
}

// ---------------- GEMM + bias + row l2norm, bf16 MFMA, fp32 out ----------------
// X fp32 [M][K], Wt bf16 [256][K], bias fp32[256] -> out fp32 [M][256] = l2norm(X@W+b)
__global__ __launch_bounds__(256) void k_gemm_mfma(
    const float* __restrict__ X, const unsigned short* __restrict__ Wt,
    const float* __restrict__ bias, float* __restrict__ out, int M, int K)
{
    __shared__ unsigned short Alds[64][72];
    __shared__ unsigned short Blds[256][72];
    const int tid = threadIdx.x;
    const int m0 = blockIdx.x * 64;
    const int wave = tid >> 6, lane = tid & 63;
    const int l15 = lane & 15, lg = lane >> 4;

    f32x4 acc[16];
    for (int i = 0; i < 16; ++i) acc[i] = (f32x4)0.0f;

    for (int k0 = 0; k0 < K; k0 += 64) {
        // A tile: fp32 -> bf16, coalesced float4 reads
        for (int p = 0; p < 4; ++p) {
            int idx = tid + p * 256;          // 1024 float4 = 64 rows x 16
            int r = idx >> 4, c4 = idx & 15;
            int row = m0 + r;
            float4 v = make_float4(0.f, 0.f, 0.f, 0.f);
            if (row < M) v = *(const float4*)(X + (size_t)row * K + k0 + c4 * 4);
            unsigned short* d = &Alds[r][c4 * 4];
            d[0] = f2bf(v.x); d[1] = f2bf(v.y); d[2] = f2bf(v.z); d[3] = f2bf(v.w);
        }
        // B tile: bf16 vector copies
        for (int p = 0; p < 8; ++p) {
            int idx = tid + p * 256;          // 2048 u16x8 = 256 j x 8
            int j = idx >> 3, k8 = idx & 7;
            *(u16x8*)&Blds[j][k8 * 8] = *(const u16x8*)(Wt + (size_t)j * K + k0 + k8 * 8);
        }
        __syncthreads();
        for (int kk = 0; kk < 2; ++kk) {
            s16x8 a = *(const s16x8*)&Alds[wave * 16 + l15][kk * 32 + lg * 8];
            for (int nt = 0; nt < 16; ++nt) {
                s16x8 b = *(const s16x8*)&Blds[nt * 16 + l15][kk * 32 + lg * 8];
                acc[nt] = __builtin_amdgcn_mfma_f32_16x16x32_bf16(a, b, acc[nt], 0, 0, 0);
            }
        }
        __syncthreads();
    }

    float sumsq[4] = {0.f, 0.f, 0.f, 0.f};
    for (int nt = 0; nt < 16; ++nt) {
        float bj = bias[nt * 16 + l15];
        for (int r = 0; r < 4; ++r) {
            float v = acc[nt][r] + bj;
            acc[nt][r] = v;
            sumsq[r] += v * v;
        }
    }
    for (int r = 0; r < 4; ++r) {
        float s = sumsq[r];
        s += __shfl_xor(s, 1); s += __shfl_xor(s, 2);
        s += __shfl_xor(s, 4); s += __shfl_xor(s, 8);
        sumsq[r] = 1.0f / fmaxf(sqrtf(s), 1e-12f);
    }
    for (int r = 0; r < 4; ++r) {
        int row = m0 + wave * 16 + lg * 4 + r;
        if (row < M) {
            for (int nt = 0; nt < 16; ++nt)
                out[(size_t)row * 256 + nt * 16 + l15] = acc[nt][r] * sumsq[r];
        }
    }
}

// ---------------- Gram via MFMA: G[i][j] += sum_m Z[m][i]*Z[m][j], Z fp32 [M][256] ----------------
// grid (4 slabs of 64 G-rows, 25 m-groups of 2048)
__global__ __launch_bounds__(256) void k_gram_mfma(const float* __restrict__ Z,
                                                   float* __restrict__ G, int M)
{
    __shared__ unsigned short Zt[256][72];     // [feature][m-chunk]
    const int tid = threadIdx.x;
    const int ib = blockIdx.x;
    const int wave = tid >> 6, lane = tid & 63;
    const int l15 = lane & 15, lg = lane >> 4;
    const int base0 = blockIdx.y * 2048;

    f32x4 acc[16];
    for (int i = 0; i < 16; ++i) acc[i] = (f32x4)0.0f;

    for (int ch = 0; ch < 32; ++ch) {
        int base = base0 + ch * 64;
        __syncthreads();
        for (int p = 0; p < 16; ++p) {
            int idx = tid + p * 256;          // 4096 float4 = 64 m x 64
            int m = idx >> 6, c4 = idx & 63;
            int row = base + m;
            float4 v = make_float4(0.f, 0.f, 0.f, 0.f);
            if (row < M) v = *(const float4*)(Z + (size_t)row * 256 + c4 * 4);
            Zt[c4 * 4 + 0][m] = f2bf(v.x); Zt[c4 * 4 + 1][m] = f2bf(v.y);
            Zt[c4 * 4 + 2][m] = f2bf(v.z); Zt[c4 * 4 + 3][m] = f2bf(v.w);
        }
        __syncthreads();
        for (int kk = 0; kk < 2; ++kk) {
            s16x8 a = *(const s16x8*)&Zt[ib * 64 + wave * 16 + l15][kk * 32 + lg * 8];
            for (int nt = 0; nt < 16; ++nt) {
                s16x8 b = *(const s16x8*)&Zt[nt * 16 + l15][kk * 32 + lg * 8];
                acc[nt] = __builtin_amdgcn_mfma_f32_16x16x32_bf16(a, b, acc[nt], 0, 0, 0);
            }
        }
    }
    for (int nt = 0; nt < 16; ++nt)
        for (int r = 0; r < 4; ++r)
            atomicAdd(&G[(ib * 64 + wave * 16 + lg * 4 + r) * 256 + nt * 16 + l15], acc[nt][r]);
}

// ---------------- HM = l2norm(PA @ S) via MFMA: PA bf16 [M][256], St bf16 [256][256] ----------------
__global__ __launch_bounds__(256) void k_hm_mfma(const unsigned short* __restrict__ PA,
                                                 const unsigned short* __restrict__ St,
                                                 float* __restrict__ out, int M)
{
    __shared__ unsigned short Alds[64][72];
    __shared__ unsigned short Blds[256][72];
    const int tid = threadIdx.x;
    const int m0 = blockIdx.x * 64;
    const int wave = tid >> 6, lane = tid & 63;
    const int l15 = lane & 15, lg = lane >> 4;

    f32x4 acc[16];
    for (int i = 0; i < 16; ++i) acc[i] = (f32x4)0.0f;

    for (int k0 = 0; k0 < 256; k0 += 64) {
        for (int p = 0; p < 2; ++p) {
            int idx = tid + p * 256;          // 512 u16x8 = 64 rows x 8
            int r = idx >> 3, k8 = idx & 7;
            int row = m0 + r;
            u16x8 v = (u16x8)0;
            if (row < M) v = *(const u16x8*)(PA + (size_t)row * 256 + k0 + k8 * 8);
            *(u16x8*)&Alds[r][k8 * 8] = v;
        }
        for (int p = 0; p < 8; ++p) {
            int idx = tid + p * 256;
            int j = idx >> 3, k8 = idx & 7;
            *(u16x8*)&Blds[j][k8 * 8] = *(const u16x8*)(St + (size_t)j * 256 + k0 + k8 * 8);
        }
        __syncthreads();
        for (int kk = 0; kk < 2; ++kk) {
            s16x8 a = *(const s16x8*)&Alds[wave * 16 + l15][kk * 32 + lg * 8];
            for (int nt = 0; nt < 16; ++nt) {
                s16x8 b = *(const s16x8*)&Blds[nt * 16 + l15][kk * 32 + lg * 8];
                acc[nt] = __builtin_amdgcn_mfma_f32_16x16x32_bf16(a, b, acc[nt], 0, 0, 0);
            }
        }
        __syncthreads();
    }

    float sumsq[4] = {0.f, 0.f, 0.f, 0.f};
    for (int nt = 0; nt < 16; ++nt)
        for (int r = 0; r < 4; ++r)
            sumsq[r] += acc[nt][r] * acc[nt][r];
    for (int r = 0; r < 4; ++r) {
        float s = sumsq[r];
        s += __shfl_xor(s, 1); s += __shfl_xor(s, 2);
        s += __shfl_xor(s, 4); s += __shfl_xor(s, 8);
        sumsq[r] = 1.0f / fmaxf(sqrtf(s), 1e-12f);
    }
    for (int r = 0; r < 4; ++r) {
        int row = m0 + wave * 16 + lg * 4 + r;
        if (row < M) {
            for (int nt = 0; nt < 16; ++nt)
                out[(size_t)row * 256 + nt * 16 + l15] = acc[nt][r] * sumsq[r];
        }
    }
}

// ---------------- small 256x256 helpers ----------------
__global__ __launch_bounds__(256) void k_max(const float* __restrict__ G, float* __restrict__ gmax)
{
    float m = -1e30f;
    for (int i = threadIdx.x; i < 65536; i += 256) m = fmaxf(m, G[i]);
    for (int s = 1; s < 64; s <<= 1) m = fmaxf(m, __shfl_xor(m, s));
    __shared__ float wm[4];
    if ((threadIdx.x & 63) == 0) wm[threadIdx.x >> 6] = m;
    __syncthreads();
    if (threadIdx.x == 0) *gmax = fmaxf(fmaxf(wm[0], wm[1]), fmaxf(wm[2], wm[3]));
}

__global__ void k_exp(const float* __restrict__ G, const float* __restrict__ gmax, float* __restrict__ E)
{
    const float inv_sqrt_n = 4.4721359549995794e-3f;   // 1/sqrt(50000)
    int i = blockIdx.x * 256 + threadIdx.x;
    E[i] = expf((G[i] - *gmax) * inv_sqrt_n);
}

__global__ __launch_bounds__(256) void k_rowsum(const float* __restrict__ E, float* __restrict__ rs)
{
    int i = blockIdx.x;
    float v = E[i * 256 + threadIdx.x];
    for (int m = 1; m < 64; m <<= 1) v += __shfl_xor(v, m);
    __shared__ float wm[4];
    if ((threadIdx.x & 63) == 0) wm[threadIdx.x >> 6] = v;
    __syncthreads();
    if (threadIdx.x == 0) rs[i] = wm[0] + wm[1] + wm[2] + wm[3];
}

__global__ void k_colsum(const float* __restrict__ E, float* __restrict__ cs)
{
    int j = threadIdx.x;
    float a = 0.f;
    for (int i = 0; i < 256; ++i) a += E[i * 256 + j];
    cs[j] = a;
}

__global__ void k_smacc(const float* __restrict__ E, const float* __restrict__ rs,
                        const float* __restrict__ cs, float* __restrict__ SMh)
{
    int i = blockIdx.x, j = threadIdx.x;
    float v = E[i * 256 + j] * rsqrtf(rs[i] + 1e-10f) * rsqrtf(cs[j] + 1e-10f);
    SMh[i * 256 + j] += 0.25f * v;
}

__global__ void k_sinit(const float* __restrict__ SMh, float* __restrict__ S)
{
    int i = blockIdx.x, j = threadIdx.x;
    S[i * 256 + j] = SMh[i * 256 + j] + (i == j ? 1.0f : 0.0f);
}

__global__ __launch_bounds__(256) void k_sgemm(const float* __restrict__ P, const float* __restrict__ SMh,
                                               float* __restrict__ Pn, float* __restrict__ S)
{
    __shared__ float pr[256];
    int i = blockIdx.x, j = threadIdx.x;
    pr[j] = P[i * 256 + j];
    __syncthreads();
    float a = 0.f;
    for (int k = 0; k < 256; ++k) a += pr[k] * SMh[k * 256 + j];
    Pn[i * 256 + j] = a;
    S[i * 256 + j] += a;
}

// ---------------- ZM = 0.5*(ZM1+ZM2) from fp32 Z's: bf16 cur and bf16 PA ----------------
__global__ void k_zm(const float* __restrict__ z1, const float* __restrict__ z2,
                     unsigned short* __restrict__ C, unsigned short* __restrict__ PA)
{
    size_t i = ((size_t)blockIdx.x * 256 + threadIdx.x) * 4;
    float4 a = *(const float4*)(z1 + i);
    float4 b = *(const float4*)(z2 + i);
    ushort4 c;
    c.x = f2bf(0.5f * (a.x + b.x)); c.y = f2bf(0.5f * (a.y + b.y));
    c.z = f2bf(0.5f * (a.z + b.z)); c.w = f2bf(0.5f * (a.w + b.w));
    *(ushort4*)(C + i) = c;
    *(ushort4*)(PA + i) = c;
}

// ---------------- CSR build ----------------
__global__ void k_hist(const int* __restrict__ src, int* __restrict__ counts)
{
    int e = blockIdx.x * 256 + threadIdx.x;
    atomicAdd(&counts[src[e]], 1);
}

__global__ __launch_bounds__(256) void k_scan(const int* __restrict__ counts,
                                              int* __restrict__ rowptr, int* __restrict__ cursor)
{
    __shared__ int sums[256];
    int t = threadIdx.x;
    const int CH = 196;
    int lo = t * CH, hi = min(lo + CH, N_NODES);
    int s = 0;
    for (int i = lo; i < hi; ++i) s += counts[i];
    sums[t] = s;
    __syncthreads();
    if (t == 0) {
        int run = 0;
        for (int q = 0; q < 256; ++q) { int tmp = sums[q]; sums[q] = run; run += tmp; }
        rowptr[N_NODES] = run;
    }
    __syncthreads();
    int run = sums[t];
    for (int i = lo; i < hi; ++i) { rowptr[i] = run; cursor[i] = run; run += counts[i]; }
}

__global__ void k_scatter(const int* __restrict__ src, const int* __restrict__ dst,
                          const float* __restrict__ val, int* __restrict__ cursor,
                          int* __restrict__ sdst, float* __restrict__ sval)
{
    int e = blockIdx.x * 256 + threadIdx.x;
    int s = src[e];
    int pos = atomicAdd(&cursor[s], 1);
    sdst[pos] = dst[e];
    sval[pos] = val[e];
}

// ---------------- SpMM layer: nxt = 0.5 * A @ cur ; PA += nxt (bf16 state) ----------------
__global__ __launch_bounds__(256) void k_spmm(const int* __restrict__ rowptr, const int* __restrict__ sdst,
                                              const float* __restrict__ sval,
                                              const unsigned short* __restrict__ cur,
                                              unsigned short* __restrict__ nxt, unsigned short* __restrict__ PA)
{
    __shared__ int ed[256];
    __shared__ float ev[256];
    int i = blockIdx.x, j = threadIdx.x;
    int lo = rowptr[i], hi = rowptr[i + 1];
    float acc = 0.f;
    for (int base = lo; base < hi; base += 256) {
        int cnt = min(hi - base, 256);
        __syncthreads();
        if (j < cnt) { ed[j] = sdst[base + j]; ev[j] = sval[base + j]; }
        __syncthreads();
        for (int q = 0; q < cnt; ++q)
            acc += ev[q] * bf2f(cur[(size_t)ed[q] * 256 + j]);
    }
    float v = 0.5f * acc;
    size_t idx = (size_t)i * 256 + j;
    nxt[idx] = f2bf(v);
    PA[idx] = f2bf(bf2f(PA[idx]) + v);
}

// ---------------- diagnostic stamps (no-op when healthy) ----------------
__global__ void k_stamp(float* __restrict__ out, float c0, float c1, float c2)
{
    if (c0 != 0.f) out[0] = c0;
    if (c1 != 0.f) out[1] = c1;
    if (c2 != 0.f) out[2] = c2;
}

extern "C" void kernel_launch(void* const* d_in, const int* in_sizes, int n_in,
                              void* d_out, int out_size, void* d_ws, size_t ws_size,
                              hipStream_t stream)
{
    const float* X1   = (const float*)d_in[0];
    const float* X2   = (const float*)d_in[1];
    const int*   esrc = (const int*)d_in[2];
    const int*   edst = (const int*)d_in[3];
    const float* eval = (const float*)d_in[4];
    const float* W1   = (const float*)d_in[5];
    const float* b1   = (const float*)d_in[6];
    const float* W2   = (const float*)d_in[7];
    const float* b2   = (const float*)d_in[8];

    float* out_zm1 = (float*)d_out;
    float* out_zm2 = out_zm1 + (size_t)N_NODES * 256;
    float* out_hm  = out_zm2 + (size_t)N_NODES * 256;

    // ---- workspace carve (~60.6 MB) ----
    char* w = (char*)d_ws;
    unsigned short* PAb   = (unsigned short*)w; w += 25600000;
    unsigned short* curA  = (unsigned short*)w; w += 25600000;
    int* sdst             = (int*)w;            w += 3200000;
    float* sval           = (float*)w;          w += 3200000;
    int* counts           = (int*)w;            w += 200192;
    int* rowptr           = (int*)w;            w += 200192;
    int* cursor           = (int*)w;            w += 200192;
    float* G              = (float*)w;          w += 262144;
    float* Emat           = (float*)w;          w += 262144;
    float* SMh            = (float*)w;          w += 262144;
    float* S              = (float*)w;          w += 262144;
    float* P2             = (float*)w;          w += 262144;
    float* P3             = (float*)w;          w += 262144;
    float* rs             = (float*)w;          w += 1024;
    float* cs             = (float*)w;          w += 1024;
    float* gmax           = (float*)w;          w += 256;
    unsigned short* Wt1   = (unsigned short*)w; w += 393216;   // 256x768 bf16
    unsigned short* Wt2   = (unsigned short*)w; w += 262144;   // 256x512 bf16
    unsigned short* St    = (unsigned short*)w; w += 131072;   // 256x256 bf16 (S^T)
    size_t ws_need = (size_t)(w - (char*)d_ws);

    unsigned short* curB  = (unsigned short*)out_hm;   // dead until k_hm

    bool sizes_ok = (n_in == 9)
        && in_sizes[0] == 38400000 && in_sizes[1] == 25600000
        && in_sizes[2] == 800000 && in_sizes[3] == 800000 && in_sizes[4] == 800000
        && in_sizes[5] == 196608 && in_sizes[6] == 256
        && in_sizes[7] == 131072 && in_sizes[8] == 256;
    float c0 = (n_in != 9) ? 1000.f : 0.f;
    float c1 = (!sizes_ok && n_in == 9) ? 2000.f : 0.f;
    float c2 = (ws_size < ws_need) ? (4000.f + (float)(ws_size / 1000000ull)) : 0.f;

    // 0) weights -> bf16 transposed
    k_wt<<<768, 256, 0, stream>>>(W1, Wt1, 768);
    k_wt<<<512, 256, 0, stream>>>(W2, Wt2, 512);

    // 1) ZM1/ZM2 via MFMA (fp32 out)
    k_gemm_mfma<<<(N_NODES + 63) / 64, 256, 0, stream>>>(X1, Wt1, b1, out_zm1, N_NODES, 768);
    k_gemm_mfma<<<(N_NODES + 63) / 64, 256, 0, stream>>>(X2, Wt2, b2, out_zm2, N_NODES, 512);

    // 2) SMh = 0.25 * (ssoftmax(ZM1) + ssoftmax(ZM2))
    hipMemsetAsync(SMh, 0, 262144, stream);
    hipMemsetAsync(G, 0, 262144, stream);
    k_gram_mfma<<<dim3(4, 25), 256, 0, stream>>>(out_zm1, G, N_NODES);
    k_max<<<1, 256, 0, stream>>>(G, gmax);
    k_exp<<<256, 256, 0, stream>>>(G, gmax, Emat);
    k_rowsum<<<256, 256, 0, stream>>>(Emat, rs);
    k_colsum<<<1, 256, 0, stream>>>(Emat, cs);
    k_smacc<<<256, 256, 0, stream>>>(Emat, rs, cs, SMh);
    hipMemsetAsync(G, 0, 262144, stream);
    k_gram_mfma<<<dim3(4, 25), 256, 0, stream>>>(out_zm2, G, N_NODES);
    k_max<<<1, 256, 0, stream>>>(G, gmax);
    k_exp<<<256, 256, 0, stream>>>(G, gmax, Emat);
    k_rowsum<<<256, 256, 0, stream>>>(Emat, rs);
    k_colsum<<<1, 256, 0, stream>>>(Emat, cs);
    k_smacc<<<256, 256, 0, stream>>>(Emat, rs, cs, SMh);

    // 3) ZM -> curA (bf16), PAb (bf16)
    k_zm<<<12500, 256, 0, stream>>>(out_zm1, out_zm2, curA, PAb);

    // 4) CSR by src
    hipMemsetAsync(counts, 0, 200192, stream);
    k_hist<<<NE / 256, 256, 0, stream>>>(esrc, counts);
    k_scan<<<1, 256, 0, stream>>>(counts, rowptr, cursor);
    k_scatter<<<NE / 256, 256, 0, stream>>>(esrc, edst, eval, cursor, sdst, sval);

    // 5) 4 propagation layers (curB parked in out_hm region)
    k_spmm<<<N_NODES, 256, 0, stream>>>(rowptr, sdst, sval, curA, curB, PAb);
    k_spmm<<<N_NODES, 256, 0, stream>>>(rowptr, sdst, sval, curB, curA, PAb);
    k_spmm<<<N_NODES, 256, 0, stream>>>(rowptr, sdst, sval, curA, curB, PAb);
    k_spmm<<<N_NODES, 256, 0, stream>>>(rowptr, sdst, sval, curB, curA, PAb);

    // 6) S = I + B + B^2 + B^3, then St = bf16(S^T)
    k_sinit<<<256, 256, 0, stream>>>(SMh, S);
    k_sgemm<<<256, 256, 0, stream>>>(SMh, SMh, P2, S);
    k_sgemm<<<256, 256, 0, stream>>>(P2, SMh, P3, S);
    k_st<<<256, 256, 0, stream>>>(S, St);

    // 7) HM = l2norm(PA @ S) via MFMA -> fp32 out (overwrites curB region — dead)
    k_hm_mfma<<<(N_NODES + 63) / 64, 256, 0, stream>>>(PAb, St, out_hm, N_NODES);

    // 8) diagnostic stamps
    k_stamp<<<1, 1, 0, stream>>>(out_zm1, c0, c1, c2);
}

// Round 9
// 1069.976 us; speedup vs baseline: 1.7728x; 1.2215x over previous
//
#include <hip/hip_runtime.h>
#include <hip/hip_bf16.h>

#define N_NODES 50000
#define NE      800000

typedef __attribute__((ext_vector_type(4))) float f32x4;
typedef __attribute__((ext_vector_type(8))) short s16x8;
typedef __attribute__((ext_vector_type(8))) unsigned short u16x8;

__device__ __forceinline__ float bf2f(unsigned short u) {
    union { unsigned int i; float f; } v; v.i = ((unsigned int)u) << 16; return v.f;
}
__device__ __forceinline__ unsigned short f2bf(float f) {
    union { unsigned int i; float f; } v; v.f = f;
    unsigned int x = v.i;
    return (unsigned short)((x + 0x7fffu + ((x >> 16) & 1u)) >> 16);  // RNE
}

// ---------------- weights: W fp32 (K,256) C-order -> Wt bf16 [256][K] ----------------
__global__ void k_wt(const float* __restrict__ W, unsigned short* __restrict__ Wt, int K)
{
    int idx = blockIdx.x * 256 + threadIdx.x;          // = j*K + k
    int j = idx / K, k = idx - j * K;
    Wt[idx] = f2bf(W[(size_t)k * 256 + j]);
}

// ---------------- S fp32 [256][256] -> St bf16 transposed: St[j][k] = S[k][j] ----------------
__global__ void k_st(const float* __restrict__ S, unsigned short* __restrict__ St)
{
    int k = blockIdx.x, j = threadIdx.x;
    St[j * 256 + k] = f2bf(S[k * 256 + j]);
}

// ---------------- GEMM + bias + row l2norm, bf16 MFMA, fp32 out ----------------
__global__ __launch_bounds__(256) void k_gemm_mfma(
    const float* __restrict__ X, const unsigned short* __restrict__ Wt,
    const float* __restrict__ bias, float* __restrict__ out, int M, int K)
{
    __shared__ unsigned short Alds[64][72];
    __shared__ unsigned short Blds[256][72];
    const int tid = threadIdx.x;
    const int m0 = blockIdx.x * 64;
    const int wave = tid >> 6, lane = tid & 63;
    const int l15 = lane & 15, lg = lane >> 4;

    f32x4 acc[16];
    for (int i = 0; i < 16; ++i) acc[i] = (f32x4)0.0f;

    for (int k0 = 0; k0 < K; k0 += 64) {
        for (int p = 0; p < 4; ++p) {
            int idx = tid + p * 256;          // 1024 float4 = 64 rows x 16
            int r = idx >> 4, c4 = idx & 15;
            int row = m0 + r;
            float4 v = make_float4(0.f, 0.f, 0.f, 0.f);
            if (row < M) v = *(const float4*)(X + (size_t)row * K + k0 + c4 * 4);
            unsigned short* d = &Alds[r][c4 * 4];
            d[0] = f2bf(v.x); d[1] = f2bf(v.y); d[2] = f2bf(v.z); d[3] = f2bf(v.w);
        }
        for (int p = 0; p < 8; ++p) {
            int idx = tid + p * 256;          // 2048 u16x8 = 256 j x 8
            int j = idx >> 3, k8 = idx & 7;
            *(u16x8*)&Blds[j][k8 * 8] = *(const u16x8*)(Wt + (size_t)j * K + k0 + k8 * 8);
        }
        __syncthreads();
        for (int kk = 0; kk < 2; ++kk) {
            s16x8 a = *(const s16x8*)&Alds[wave * 16 + l15][kk * 32 + lg * 8];
            for (int nt = 0; nt < 16; ++nt) {
                s16x8 b = *(const s16x8*)&Blds[nt * 16 + l15][kk * 32 + lg * 8];
                acc[nt] = __builtin_amdgcn_mfma_f32_16x16x32_bf16(a, b, acc[nt], 0, 0, 0);
            }
        }
        __syncthreads();
    }

    float sumsq[4] = {0.f, 0.f, 0.f, 0.f};
    for (int nt = 0; nt < 16; ++nt) {
        float bj = bias[nt * 16 + l15];
        for (int r = 0; r < 4; ++r) {
            float v = acc[nt][r] + bj;
            acc[nt][r] = v;
            sumsq[r] += v * v;
        }
    }
    for (int r = 0; r < 4; ++r) {
        float s = sumsq[r];
        s += __shfl_xor(s, 1); s += __shfl_xor(s, 2);
        s += __shfl_xor(s, 4); s += __shfl_xor(s, 8);
        sumsq[r] = 1.0f / fmaxf(sqrtf(s), 1e-12f);
    }
    for (int r = 0; r < 4; ++r) {
        int row = m0 + wave * 16 + lg * 4 + r;
        if (row < M) {
            for (int nt = 0; nt < 16; ++nt)
                out[(size_t)row * 256 + nt * 16 + l15] = acc[nt][r] * sumsq[r];
        }
    }
}

// ---------------- Gram via MFMA, split-K + swizzled LDS transpose ----------------
// grid (4 slabs, 98 m-groups of 512, 2 matrices). G via fp32 atomics.
// LDS: element (feature f, m) at Zt[f][m ^ ((f>>2 & 7)<<3)]  — 8-granule XOR swizzle.
__global__ __launch_bounds__(256) void k_gram_mfma(
    const float* __restrict__ Z1, const float* __restrict__ Z2,
    float* __restrict__ G1, float* __restrict__ G2, int M)
{
    __shared__ unsigned short Zt[256][72];
    const float* Z = blockIdx.z ? Z2 : Z1;
    float* G = blockIdx.z ? G2 : G1;
    const int tid = threadIdx.x;
    const int ib = blockIdx.x;
    const int wave = tid >> 6, lane = tid & 63;
    const int l15 = lane & 15, lg = lane >> 4;
    const int TC = (M + 63) >> 6;                 // 782 chunks of 64 rows
    const int c0 = blockIdx.y * 8;
    const int c1 = min(c0 + 8, TC);

    const int ja = ib * 64 + wave * 16 + l15;     // A-operand feature row
    const int sa = ((ja >> 2) & 7) << 3;          // its read swizzle

    f32x4 acc[16];
    for (int i = 0; i < 16; ++i) acc[i] = (f32x4)0.0f;

    for (int ch = c0; ch < c1; ++ch) {
        int base = ch * 64;
        __syncthreads();
        for (int p = 0; p < 16; ++p) {
            int idx = tid + p * 256;              // 4096 float4 = 64 m x 64 c4
            int m = idx >> 6, c4 = idx & 63;
            int row = base + m;
            float4 v = make_float4(0.f, 0.f, 0.f, 0.f);
            if (row < M) v = *(const float4*)(Z + (size_t)row * 256 + c4 * 4);
            int cs = m ^ ((c4 & 7) << 3);         // (f>>2)&7 == c4&7 for f = c4*4+q
            int f0 = c4 * 4;
            Zt[f0 + 0][cs] = f2bf(v.x); Zt[f0 + 1][cs] = f2bf(v.y);
            Zt[f0 + 2][cs] = f2bf(v.z); Zt[f0 + 3][cs] = f2bf(v.w);
        }
        __syncthreads();
        for (int kk = 0; kk < 2; ++kk) {
            s16x8 a = *(const s16x8*)&Zt[ja][(kk * 32 + lg * 8) ^ sa];
            for (int nt = 0; nt < 16; ++nt) {
                int jb = nt * 16 + l15;
                int sb = ((jb >> 2) & 7) << 3;
                s16x8 b = *(const s16x8*)&Zt[jb][(kk * 32 + lg * 8) ^ sb];
                acc[nt] = __builtin_amdgcn_mfma_f32_16x16x32_bf16(a, b, acc[nt], 0, 0, 0);
            }
        }
    }
    for (int nt = 0; nt < 16; ++nt)
        for (int r = 0; r < 4; ++r)
            atomicAdd(&G[(ib * 64 + wave * 16 + lg * 4 + r) * 256 + nt * 16 + l15], acc[nt][r]);
}

// ---------------- HM = l2norm(PA @ S) via MFMA ----------------
__global__ __launch_bounds__(256) void k_hm_mfma(const unsigned short* __restrict__ PA,
                                                 const unsigned short* __restrict__ St,
                                                 float* __restrict__ out, int M)
{
    __shared__ unsigned short Alds[64][72];
    __shared__ unsigned short Blds[256][72];
    const int tid = threadIdx.x;
    const int m0 = blockIdx.x * 64;
    const int wave = tid >> 6, lane = tid & 63;
    const int l15 = lane & 15, lg = lane >> 4;

    f32x4 acc[16];
    for (int i = 0; i < 16; ++i) acc[i] = (f32x4)0.0f;

    for (int k0 = 0; k0 < 256; k0 += 64) {
        for (int p = 0; p < 2; ++p) {
            int idx = tid + p * 256;
            int r = idx >> 3, k8 = idx & 7;
            int row = m0 + r;
            u16x8 v = (u16x8)0;
            if (row < M) v = *(const u16x8*)(PA + (size_t)row * 256 + k0 + k8 * 8);
            *(u16x8*)&Alds[r][k8 * 8] = v;
        }
        for (int p = 0; p < 8; ++p) {
            int idx = tid + p * 256;
            int j = idx >> 3, k8 = idx & 7;
            *(u16x8*)&Blds[j][k8 * 8] = *(const u16x8*)(St + (size_t)j * 256 + k0 + k8 * 8);
        }
        __syncthreads();
        for (int kk = 0; kk < 2; ++kk) {
            s16x8 a = *(const s16x8*)&Alds[wave * 16 + l15][kk * 32 + lg * 8];
            for (int nt = 0; nt < 16; ++nt) {
                s16x8 b = *(const s16x8*)&Blds[nt * 16 + l15][kk * 32 + lg * 8];
                acc[nt] = __builtin_amdgcn_mfma_f32_16x16x32_bf16(a, b, acc[nt], 0, 0, 0);
            }
        }
        __syncthreads();
    }

    float sumsq[4] = {0.f, 0.f, 0.f, 0.f};
    for (int nt = 0; nt < 16; ++nt)
        for (int r = 0; r < 4; ++r)
            sumsq[r] += acc[nt][r] * acc[nt][r];
    for (int r = 0; r < 4; ++r) {
        float s = sumsq[r];
        s += __shfl_xor(s, 1); s += __shfl_xor(s, 2);
        s += __shfl_xor(s, 4); s += __shfl_xor(s, 8);
        sumsq[r] = 1.0f / fmaxf(sqrtf(s), 1e-12f);
    }
    for (int r = 0; r < 4; ++r) {
        int row = m0 + wave * 16 + lg * 4 + r;
        if (row < M) {
            for (int nt = 0; nt < 16; ++nt)
                out[(size_t)row * 256 + nt * 16 + l15] = acc[nt][r] * sumsq[r];
        }
    }
}

// ---------------- small 256x256 helpers ----------------
__global__ __launch_bounds__(256) void k_max(const float* __restrict__ G, float* __restrict__ gmax)
{
    float m = -1e30f;
    for (int i = threadIdx.x; i < 65536; i += 256) m = fmaxf(m, G[i]);
    for (int s = 1; s < 64; s <<= 1) m = fmaxf(m, __shfl_xor(m, s));
    __shared__ float wm[4];
    if ((threadIdx.x & 63) == 0) wm[threadIdx.x >> 6] = m;
    __syncthreads();
    if (threadIdx.x == 0) *gmax = fmaxf(fmaxf(wm[0], wm[1]), fmaxf(wm[2], wm[3]));
}

__global__ void k_exp(const float* __restrict__ G, const float* __restrict__ gmax, float* __restrict__ E)
{
    const float inv_sqrt_n = 4.4721359549995794e-3f;   // 1/sqrt(50000)
    int i = blockIdx.x * 256 + threadIdx.x;
    E[i] = expf((G[i] - *gmax) * inv_sqrt_n);
}

__global__ __launch_bounds__(256) void k_rowsum(const float* __restrict__ E, float* __restrict__ rs)
{
    int i = blockIdx.x;
    float v = E[i * 256 + threadIdx.x];
    for (int m = 1; m < 64; m <<= 1) v += __shfl_xor(v, m);
    __shared__ float wm[4];
    if ((threadIdx.x & 63) == 0) wm[threadIdx.x >> 6] = v;
    __syncthreads();
    if (threadIdx.x == 0) rs[i] = wm[0] + wm[1] + wm[2] + wm[3];
}

__global__ void k_colsum(const float* __restrict__ E, float* __restrict__ cs)
{
    int j = threadIdx.x;
    float a = 0.f;
    for (int i = 0; i < 256; ++i) a += E[i * 256 + j];
    cs[j] = a;
}

__global__ void k_smacc(const float* __restrict__ E, const float* __restrict__ rs,
                        const float* __restrict__ cs, float* __restrict__ SMh)
{
    int i = blockIdx.x, j = threadIdx.x;
    float v = E[i * 256 + j] * rsqrtf(rs[i] + 1e-10f) * rsqrtf(cs[j] + 1e-10f);
    SMh[i * 256 + j] += 0.25f * v;
}

__global__ void k_sinit(const float* __restrict__ SMh, float* __restrict__ S)
{
    int i = blockIdx.x, j = threadIdx.x;
    S[i * 256 + j] = SMh[i * 256 + j] + (i == j ? 1.0f : 0.0f);
}

__global__ __launch_bounds__(256) void k_sgemm(const float* __restrict__ P, const float* __restrict__ SMh,
                                               float* __restrict__ Pn, float* __restrict__ S)
{
    __shared__ float pr[256];
    int i = blockIdx.x, j = threadIdx.x;
    pr[j] = P[i * 256 + j];
    __syncthreads();
    float a = 0.f;
    for (int k = 0; k < 256; ++k) a += pr[k] * SMh[k * 256 + j];
    Pn[i * 256 + j] = a;
    S[i * 256 + j] += a;
}

// ---------------- ZM = 0.5*(ZM1+ZM2): bf16 cur and bf16 PA ----------------
__global__ void k_zm(const float* __restrict__ z1, const float* __restrict__ z2,
                     unsigned short* __restrict__ C, unsigned short* __restrict__ PA)
{
    size_t i = ((size_t)blockIdx.x * 256 + threadIdx.x) * 4;
    float4 a = *(const float4*)(z1 + i);
    float4 b = *(const float4*)(z2 + i);
    ushort4 c;
    c.x = f2bf(0.5f * (a.x + b.x)); c.y = f2bf(0.5f * (a.y + b.y));
    c.z = f2bf(0.5f * (a.z + b.z)); c.w = f2bf(0.5f * (a.w + b.w));
    *(ushort4*)(C + i) = c;
    *(ushort4*)(PA + i) = c;
}

// ---------------- CSR build ----------------
__global__ void k_hist(const int* __restrict__ src, int* __restrict__ counts)
{
    int e = blockIdx.x * 256 + threadIdx.x;
    atomicAdd(&counts[src[e]], 1);
}

__global__ __launch_bounds__(256) void k_scan(const int* __restrict__ counts,
                                              int* __restrict__ rowptr, int* __restrict__ cursor)
{
    __shared__ int sums[256];
    int t = threadIdx.x;
    const int CH = 196;
    int lo = t * CH, hi = min(lo + CH, N_NODES);
    int s = 0;
    for (int i = lo; i < hi; ++i) s += counts[i];
    sums[t] = s;
    __syncthreads();
    if (t == 0) {
        int run = 0;
        for (int q = 0; q < 256; ++q) { int tmp = sums[q]; sums[q] = run; run += tmp; }
        rowptr[N_NODES] = run;
    }
    __syncthreads();
    int run = sums[t];
    for (int i = lo; i < hi; ++i) { rowptr[i] = run; cursor[i] = run; run += counts[i]; }
}

__global__ void k_scatter(const int* __restrict__ src, const int* __restrict__ dst,
                          const float* __restrict__ val, int* __restrict__ cursor,
                          int* __restrict__ sdst, float* __restrict__ sval)
{
    int e = blockIdx.x * 256 + threadIdx.x;
    int s = src[e];
    int pos = atomicAdd(&cursor[s], 1);
    sdst[pos] = dst[e];
    sval[pos] = val[e];
}

// ---------------- SpMM layer: nxt = 0.5 * A @ cur ; PA += nxt (bf16 state) ----------------
__global__ __launch_bounds__(256) void k_spmm(const int* __restrict__ rowptr, const int* __restrict__ sdst,
                                              const float* __restrict__ sval,
                                              const unsigned short* __restrict__ cur,
                                              unsigned short* __restrict__ nxt, unsigned short* __restrict__ PA)
{
    __shared__ int ed[256];
    __shared__ float ev[256];
    int i = blockIdx.x, j = threadIdx.x;
    int lo = rowptr[i], hi = rowptr[i + 1];
    float acc = 0.f;
    for (int base = lo; base < hi; base += 256) {
        int cnt = min(hi - base, 256);
        __syncthreads();
        if (j < cnt) { ed[j] = sdst[base + j]; ev[j] = sval[base + j]; }
        __syncthreads();
        for (int q = 0; q < cnt; ++q)
            acc += ev[q] * bf2f(cur[(size_t)ed[q] * 256 + j]);
    }
    float v = 0.5f * acc;
    size_t idx = (size_t)i * 256 + j;
    nxt[idx] = f2bf(v);
    PA[idx] = f2bf(bf2f(PA[idx]) + v);
}

// ---------------- diagnostic stamps ----------------
__global__ void k_stamp(float* __restrict__ out, float c0, float c1, float c2)
{
    if (c0 != 0.f) out[0] = c0;
    if (c1 != 0.f) out[1] = c1;
    if (c2 != 0.f) out[2] = c2;
}

extern "C" void kernel_launch(void* const* d_in, const int* in_sizes, int n_in,
                              void* d_out, int out_size, void* d_ws, size_t ws_size,
                              hipStream_t stream)
{
    const float* X1   = (const float*)d_in[0];
    const float* X2   = (const float*)d_in[1];
    const int*   esrc = (const int*)d_in[2];
    const int*   edst = (const int*)d_in[3];
    const float* eval = (const float*)d_in[4];
    const float* W1   = (const float*)d_in[5];
    const float* b1   = (const float*)d_in[6];
    const float* W2   = (const float*)d_in[7];
    const float* b2   = (const float*)d_in[8];

    float* out_zm1 = (float*)d_out;
    float* out_zm2 = out_zm1 + (size_t)N_NODES * 256;
    float* out_hm  = out_zm2 + (size_t)N_NODES * 256;

    // ---- workspace carve (~60.9 MB) ----
    char* w = (char*)d_ws;
    unsigned short* PAb   = (unsigned short*)w; w += 25600000;
    unsigned short* curA  = (unsigned short*)w; w += 25600000;
    int* sdst             = (int*)w;            w += 3200000;
    float* sval           = (float*)w;          w += 3200000;
    int* counts           = (int*)w;            w += 200192;
    int* rowptr           = (int*)w;            w += 200192;
    int* cursor           = (int*)w;            w += 200192;
    float* G1             = (float*)w;          w += 262144;
    float* G2             = (float*)w;          w += 262144;
    float* Emat           = (float*)w;          w += 262144;
    float* SMh            = (float*)w;          w += 262144;
    float* S              = (float*)w;          w += 262144;
    float* P2             = (float*)w;          w += 262144;
    float* P3             = (float*)w;          w += 262144;
    float* rs             = (float*)w;          w += 1024;
    float* cs             = (float*)w;          w += 1024;
    float* gmax           = (float*)w;          w += 256;
    unsigned short* Wt1   = (unsigned short*)w; w += 393216;
    unsigned short* Wt2   = (unsigned short*)w; w += 262144;
    unsigned short* St    = (unsigned short*)w; w += 131072;
    size_t ws_need = (size_t)(w - (char*)d_ws);

    unsigned short* curB  = (unsigned short*)out_hm;   // dead until k_hm

    bool sizes_ok = (n_in == 9)
        && in_sizes[0] == 38400000 && in_sizes[1] == 25600000
        && in_sizes[2] == 800000 && in_sizes[3] == 800000 && in_sizes[4] == 800000
        && in_sizes[5] == 196608 && in_sizes[6] == 256
        && in_sizes[7] == 131072 && in_sizes[8] == 256;
    float c0 = (n_in != 9) ? 1000.f : 0.f;
    float c1 = (!sizes_ok && n_in == 9) ? 2000.f : 0.f;
    float c2 = (ws_size < ws_need) ? (4000.f + (float)(ws_size / 1000000ull)) : 0.f;

    // 0) weights -> bf16 transposed
    k_wt<<<768, 256, 0, stream>>>(W1, Wt1, 768);
    k_wt<<<512, 256, 0, stream>>>(W2, Wt2, 512);

    // 1) ZM1/ZM2 via MFMA
    k_gemm_mfma<<<(N_NODES + 63) / 64, 256, 0, stream>>>(X1, Wt1, b1, out_zm1, N_NODES, 768);
    k_gemm_mfma<<<(N_NODES + 63) / 64, 256, 0, stream>>>(X2, Wt2, b2, out_zm2, N_NODES, 512);

    // 2) both Grams in one dispatch, then the two softmax chains
    hipMemsetAsync(SMh, 0, 262144, stream);
    hipMemsetAsync(G1, 0, 262144, stream);
    hipMemsetAsync(G2, 0, 262144, stream);
    k_gram_mfma<<<dim3(4, 98, 2), 256, 0, stream>>>(out_zm1, out_zm2, G1, G2, N_NODES);
    k_max<<<1, 256, 0, stream>>>(G1, gmax);
    k_exp<<<256, 256, 0, stream>>>(G1, gmax, Emat);
    k_rowsum<<<256, 256, 0, stream>>>(Emat, rs);
    k_colsum<<<1, 256, 0, stream>>>(Emat, cs);
    k_smacc<<<256, 256, 0, stream>>>(Emat, rs, cs, SMh);
    k_max<<<1, 256, 0, stream>>>(G2, gmax);
    k_exp<<<256, 256, 0, stream>>>(G2, gmax, Emat);
    k_rowsum<<<256, 256, 0, stream>>>(Emat, rs);
    k_colsum<<<1, 256, 0, stream>>>(Emat, cs);
    k_smacc<<<256, 256, 0, stream>>>(Emat, rs, cs, SMh);

    // 3) ZM -> curA (bf16), PAb (bf16)
    k_zm<<<12500, 256, 0, stream>>>(out_zm1, out_zm2, curA, PAb);

    // 4) CSR by src
    hipMemsetAsync(counts, 0, 200192, stream);
    k_hist<<<NE / 256, 256, 0, stream>>>(esrc, counts);
    k_scan<<<1, 256, 0, stream>>>(counts, rowptr, cursor);
    k_scatter<<<NE / 256, 256, 0, stream>>>(esrc, edst, eval, cursor, sdst, sval);

    // 5) 4 propagation layers (curB parked in out_hm region)
    k_spmm<<<N_NODES, 256, 0, stream>>>(rowptr, sdst, sval, curA, curB, PAb);
    k_spmm<<<N_NODES, 256, 0, stream>>>(rowptr, sdst, sval, curB, curA, PAb);
    k_spmm<<<N_NODES, 256, 0, stream>>>(rowptr, sdst, sval, curA, curB, PAb);
    k_spmm<<<N_NODES, 256, 0, stream>>>(rowptr, sdst, sval, curB, curA, PAb);

    // 6) S = I + B + B^2 + B^3, then St = bf16(S^T)
    k_sinit<<<256, 256, 0, stream>>>(SMh, S);
    k_sgemm<<<256, 256, 0, stream>>>(SMh, SMh, P2, S);
    k_sgemm<<<256, 256, 0, stream>>>(P2, SMh, P3, S);
    k_st<<<256, 256, 0, stream>>>(S, St);

    // 7) HM = l2norm(PA @ S) via MFMA
    k_hm_mfma<<<(N_NODES + 63) / 64, 256, 0, stream>>>(PAb, St, out_hm, N_NODES);

    // 8) diagnostic stamps
    k_stamp<<<1, 1, 0, stream>>>(out_zm1, c0, c1, c2);
}

// Round 10
// 1020.777 us; speedup vs baseline: 1.8583x; 1.0482x over previous
//
#include <hip/hip_runtime.h>
#include <hip/hip_bf16.h>

#define N_NODES 50000
#define NE      800000

typedef __attribute__((ext_vector_type(4))) float f32x4;
typedef __attribute__((ext_vector_type(8))) short s16x8;
typedef __attribute__((ext_vector_type(8))) unsigned short u16x8;

__device__ __forceinline__ float bf2f(unsigned short u) {
    union { unsigned int i; float f; } v; v.i = ((unsigned int)u) << 16; return v.f;
}
__device__ __forceinline__ unsigned short f2bf(float f) {
    union { unsigned int i; float f; } v; v.f = f;
    unsigned int x = v.i;
    return (unsigned short)((x + 0x7fffu + ((x >> 16) & 1u)) >> 16);  // RNE
}

// ---------------- weights: W fp32 (K,256) C-order -> Wt bf16 [256][K] ----------------
__global__ void k_wt(const float* __restrict__ W, unsigned short* __restrict__ Wt, int K)
{
    int idx = blockIdx.x * 256 + threadIdx.x;          // = j*K + k
    int j = idx / K, k = idx - j * K;
    Wt[idx] = f2bf(W[(size_t)k * 256 + j]);
}

// ---------------- S fp32 [256][256] -> St bf16 transposed ----------------
__global__ void k_st(const float* __restrict__ S, unsigned short* __restrict__ St)
{
    int k = blockIdx.x, j = threadIdx.x;
    St[j * 256 + k] = f2bf(S[k * 256 + j]);
}

// ---------------- GEMM + bias + row l2norm, bf16 MFMA; dual store fp32 + bf16 ----------------
__global__ __launch_bounds__(256) void k_gemm_mfma(
    const float* __restrict__ X, const unsigned short* __restrict__ Wt,
    const float* __restrict__ bias, float* __restrict__ out,
    unsigned short* __restrict__ Zb, int M, int K)
{
    __shared__ unsigned short Alds[64][72];
    __shared__ unsigned short Blds[256][72];
    const int tid = threadIdx.x;
    const int m0 = blockIdx.x * 64;
    const int wave = tid >> 6, lane = tid & 63;
    const int l15 = lane & 15, lg = lane >> 4;

    f32x4 acc[16];
    for (int i = 0; i < 16; ++i) acc[i] = (f32x4)0.0f;

    for (int k0 = 0; k0 < K; k0 += 64) {
        for (int p = 0; p < 4; ++p) {
            int idx = tid + p * 256;          // 1024 float4 = 64 rows x 16
            int r = idx >> 4, c4 = idx & 15;
            int row = m0 + r;
            float4 v = make_float4(0.f, 0.f, 0.f, 0.f);
            if (row < M) v = *(const float4*)(X + (size_t)row * K + k0 + c4 * 4);
            unsigned short* d = &Alds[r][c4 * 4];
            d[0] = f2bf(v.x); d[1] = f2bf(v.y); d[2] = f2bf(v.z); d[3] = f2bf(v.w);
        }
        for (int p = 0; p < 8; ++p) {
            int idx = tid + p * 256;          // 2048 u16x8 = 256 j x 8
            int j = idx >> 3, k8 = idx & 7;
            *(u16x8*)&Blds[j][k8 * 8] = *(const u16x8*)(Wt + (size_t)j * K + k0 + k8 * 8);
        }
        __syncthreads();
        for (int kk = 0; kk < 2; ++kk) {
            s16x8 a = *(const s16x8*)&Alds[wave * 16 + l15][kk * 32 + lg * 8];
            for (int nt = 0; nt < 16; ++nt) {
                s16x8 b = *(const s16x8*)&Blds[nt * 16 + l15][kk * 32 + lg * 8];
                acc[nt] = __builtin_amdgcn_mfma_f32_16x16x32_bf16(a, b, acc[nt], 0, 0, 0);
            }
        }
        __syncthreads();
    }

    float sumsq[4] = {0.f, 0.f, 0.f, 0.f};
    for (int nt = 0; nt < 16; ++nt) {
        float bj = bias[nt * 16 + l15];
        for (int r = 0; r < 4; ++r) {
            float v = acc[nt][r] + bj;
            acc[nt][r] = v;
            sumsq[r] += v * v;
        }
    }
    for (int r = 0; r < 4; ++r) {
        float s = sumsq[r];
        s += __shfl_xor(s, 1); s += __shfl_xor(s, 2);
        s += __shfl_xor(s, 4); s += __shfl_xor(s, 8);
        sumsq[r] = 1.0f / fmaxf(sqrtf(s), 1e-12f);
    }
    for (int r = 0; r < 4; ++r) {
        int row = m0 + wave * 16 + lg * 4 + r;
        if (row < M) {
            for (int nt = 0; nt < 16; ++nt) {
                float v = acc[nt][r] * sumsq[r];
                out[(size_t)row * 256 + nt * 16 + l15] = v;
                Zb[(size_t)row * 256 + nt * 16 + l15] = f2bf(v);
            }
        }
    }
}

// ---------------- Gram via MFMA: bf16 source, 128-row slabs, 8-wave blocks ----------------
// grid (2 slabs, 49 m-groups of 1024, 2 matrices)
__global__ __launch_bounds__(512) void k_gram_mfma(
    const unsigned short* __restrict__ Zb1, const unsigned short* __restrict__ Zb2,
    float* __restrict__ G1, float* __restrict__ G2, int M)
{
    __shared__ unsigned short Zt[256][72];
    const unsigned short* Z = blockIdx.z ? Zb2 : Zb1;
    float* G = blockIdx.z ? G2 : G1;
    const int tid = threadIdx.x;
    const int ib = blockIdx.x;
    const int wave = tid >> 6, lane = tid & 63;
    const int l15 = lane & 15, lg = lane >> 4;
    const int TC = (M + 63) >> 6;                 // 782
    const int c0 = blockIdx.y * 16;
    const int c1 = min(c0 + 16, TC);

    const int ja = ib * 128 + wave * 16 + l15;    // A-operand feature row
    const int sa = ((ja >> 2) & 7) << 3;

    f32x4 acc[16];
    for (int i = 0; i < 16; ++i) acc[i] = (f32x4)0.0f;

    for (int ch = c0; ch < c1; ++ch) {
        int base = ch * 64;
        __syncthreads();
        for (int p = 0; p < 4; ++p) {
            int idx = tid + p * 512;              // 2048 u16x8 = 64 m x 32 c8
            int m = idx >> 5, c8 = idx & 31;
            int row = base + m;
            u16x8 v = (u16x8)0;
            if (row < M) v = *(const u16x8*)(Z + (size_t)row * 256 + c8 * 8);
            for (int q = 0; q < 8; ++q) {
                int f = c8 * 8 + q;
                int cs = m ^ (((f >> 2) & 7) << 3);
                Zt[f][cs] = v[q];
            }
        }
        __syncthreads();
        for (int kk = 0; kk < 2; ++kk) {
            s16x8 a = *(const s16x8*)&Zt[ja][(kk * 32 + lg * 8) ^ sa];
            for (int nt = 0; nt < 16; ++nt) {
                int jb = nt * 16 + l15;
                int sb = ((jb >> 2) & 7) << 3;
                s16x8 b = *(const s16x8*)&Zt[jb][(kk * 32 + lg * 8) ^ sb];
                acc[nt] = __builtin_amdgcn_mfma_f32_16x16x32_bf16(a, b, acc[nt], 0, 0, 0);
            }
        }
    }
    for (int nt = 0; nt < 16; ++nt)
        for (int r = 0; r < 4; ++r)
            atomicAdd(&G[(ib * 128 + wave * 16 + lg * 4 + r) * 256 + nt * 16 + l15], acc[nt][r]);
}

// ---------------- HM = l2norm(PA @ S) via MFMA ----------------
__global__ __launch_bounds__(256) void k_hm_mfma(const unsigned short* __restrict__ PA,
                                                 const unsigned short* __restrict__ St,
                                                 float* __restrict__ out, int M)
{
    __shared__ unsigned short Alds[64][72];
    __shared__ unsigned short Blds[256][72];
    const int tid = threadIdx.x;
    const int m0 = blockIdx.x * 64;
    const int wave = tid >> 6, lane = tid & 63;
    const int l15 = lane & 15, lg = lane >> 4;

    f32x4 acc[16];
    for (int i = 0; i < 16; ++i) acc[i] = (f32x4)0.0f;

    for (int k0 = 0; k0 < 256; k0 += 64) {
        for (int p = 0; p < 2; ++p) {
            int idx = tid + p * 256;
            int r = idx >> 3, k8 = idx & 7;
            int row = m0 + r;
            u16x8 v = (u16x8)0;
            if (row < M) v = *(const u16x8*)(PA + (size_t)row * 256 + k0 + k8 * 8);
            *(u16x8*)&Alds[r][k8 * 8] = v;
        }
        for (int p = 0; p < 8; ++p) {
            int idx = tid + p * 256;
            int j = idx >> 3, k8 = idx & 7;
            *(u16x8*)&Blds[j][k8 * 8] = *(const u16x8*)(St + (size_t)j * 256 + k0 + k8 * 8);
        }
        __syncthreads();
        for (int kk = 0; kk < 2; ++kk) {
            s16x8 a = *(const s16x8*)&Alds[wave * 16 + l15][kk * 32 + lg * 8];
            for (int nt = 0; nt < 16; ++nt) {
                s16x8 b = *(const s16x8*)&Blds[nt * 16 + l15][kk * 32 + lg * 8];
                acc[nt] = __builtin_amdgcn_mfma_f32_16x16x32_bf16(a, b, acc[nt], 0, 0, 0);
            }
        }
        __syncthreads();
    }

    float sumsq[4] = {0.f, 0.f, 0.f, 0.f};
    for (int nt = 0; nt < 16; ++nt)
        for (int r = 0; r < 4; ++r)
            sumsq[r] += acc[nt][r] * acc[nt][r];
    for (int r = 0; r < 4; ++r) {
        float s = sumsq[r];
        s += __shfl_xor(s, 1); s += __shfl_xor(s, 2);
        s += __shfl_xor(s, 4); s += __shfl_xor(s, 8);
        sumsq[r] = 1.0f / fmaxf(sqrtf(s), 1e-12f);
    }
    for (int r = 0; r < 4; ++r) {
        int row = m0 + wave * 16 + lg * 4 + r;
        if (row < M) {
            for (int nt = 0; nt < 16; ++nt)
                out[(size_t)row * 256 + nt * 16 + l15] = acc[nt][r] * sumsq[r];
        }
    }
}

// ---------------- small 256x256 helpers ----------------
__global__ __launch_bounds__(256) void k_max(const float* __restrict__ G, float* __restrict__ gmax)
{
    float m = -1e30f;
    for (int i = threadIdx.x; i < 65536; i += 256) m = fmaxf(m, G[i]);
    for (int s = 1; s < 64; s <<= 1) m = fmaxf(m, __shfl_xor(m, s));
    __shared__ float wm[4];
    if ((threadIdx.x & 63) == 0) wm[threadIdx.x >> 6] = m;
    __syncthreads();
    if (threadIdx.x == 0) *gmax = fmaxf(fmaxf(wm[0], wm[1]), fmaxf(wm[2], wm[3]));
}

__global__ void k_exp(const float* __restrict__ G, const float* __restrict__ gmax, float* __restrict__ E)
{
    const float inv_sqrt_n = 4.4721359549995794e-3f;   // 1/sqrt(50000)
    int i = blockIdx.x * 256 + threadIdx.x;
    E[i] = expf((G[i] - *gmax) * inv_sqrt_n);
}

__global__ __launch_bounds__(256) void k_rowsum(const float* __restrict__ E, float* __restrict__ rs)
{
    int i = blockIdx.x;
    float v = E[i * 256 + threadIdx.x];
    for (int m = 1; m < 64; m <<= 1) v += __shfl_xor(v, m);
    __shared__ float wm[4];
    if ((threadIdx.x & 63) == 0) wm[threadIdx.x >> 6] = v;
    __syncthreads();
    if (threadIdx.x == 0) rs[i] = wm[0] + wm[1] + wm[2] + wm[3];
}

__global__ void k_colsum(const float* __restrict__ E, float* __restrict__ cs)
{
    int j = threadIdx.x;
    float a = 0.f;
    for (int i = 0; i < 256; ++i) a += E[i * 256 + j];
    cs[j] = a;
}

__global__ void k_smacc(const float* __restrict__ E, const float* __restrict__ rs,
                        const float* __restrict__ cs, float* __restrict__ SMh)
{
    int i = blockIdx.x, j = threadIdx.x;
    float v = E[i * 256 + j] * rsqrtf(rs[i] + 1e-10f) * rsqrtf(cs[j] + 1e-10f);
    SMh[i * 256 + j] += 0.25f * v;
}

__global__ void k_sinit(const float* __restrict__ SMh, float* __restrict__ S)
{
    int i = blockIdx.x, j = threadIdx.x;
    S[i * 256 + j] = SMh[i * 256 + j] + (i == j ? 1.0f : 0.0f);
}

__global__ __launch_bounds__(256) void k_sgemm(const float* __restrict__ P, const float* __restrict__ SMh,
                                               float* __restrict__ Pn, float* __restrict__ S)
{
    __shared__ float pr[256];
    int i = blockIdx.x, j = threadIdx.x;
    pr[j] = P[i * 256 + j];
    __syncthreads();
    float a = 0.f;
    for (int k = 0; k < 256; ++k) a += pr[k] * SMh[k * 256 + j];
    Pn[i * 256 + j] = a;
    S[i * 256 + j] += a;
}

// ---------------- ZM: in-place average of the two bf16 copies ----------------
__global__ void k_zm(unsigned short* __restrict__ A, unsigned short* __restrict__ B)
{
    size_t i = ((size_t)blockIdx.x * 256 + threadIdx.x) * 8;
    u16x8 a = *(const u16x8*)(A + i), b = *(const u16x8*)(B + i);
    u16x8 c;
    for (int q = 0; q < 8; ++q) c[q] = f2bf(0.5f * (bf2f(a[q]) + bf2f(b[q])));
    *(u16x8*)(A + i) = c;
    *(u16x8*)(B + i) = c;
}

// ---------------- CSR build ----------------
__global__ void k_hist(const int* __restrict__ src, int* __restrict__ counts)
{
    int e = blockIdx.x * 256 + threadIdx.x;
    atomicAdd(&counts[src[e]], 1);
}

__global__ __launch_bounds__(256) void k_scan(const int* __restrict__ counts,
                                              int* __restrict__ rowptr, int* __restrict__ cursor)
{
    __shared__ int sums[256];
    int t = threadIdx.x;
    const int CH = 196;
    int lo = t * CH, hi = min(lo + CH, N_NODES);
    int s = 0;
    for (int i = lo; i < hi; ++i) s += counts[i];
    sums[t] = s;
    __syncthreads();
    if (t == 0) {
        int run = 0;
        for (int q = 0; q < 256; ++q) { int tmp = sums[q]; sums[q] = run; run += tmp; }
        rowptr[N_NODES] = run;
    }
    __syncthreads();
    int run = sums[t];
    for (int i = lo; i < hi; ++i) { rowptr[i] = run; cursor[i] = run; run += counts[i]; }
}

__global__ void k_scatter(const int* __restrict__ src, const int* __restrict__ dst,
                          const float* __restrict__ val, int* __restrict__ cursor,
                          int* __restrict__ sdst, float* __restrict__ sval)
{
    int e = blockIdx.x * 256 + threadIdx.x;
    int s = src[e];
    int pos = atomicAdd(&cursor[s], 1);
    sdst[pos] = dst[e];
    sval[pos] = val[e];
}

// ---------------- SpMM layer: nxt = 0.5 * A @ cur ; PA += nxt (bf16, unroll-4 ILP) ----------------
__global__ __launch_bounds__(256) void k_spmm(const int* __restrict__ rowptr, const int* __restrict__ sdst,
                                              const float* __restrict__ sval,
                                              const unsigned short* __restrict__ cur,
                                              unsigned short* __restrict__ nxt, unsigned short* __restrict__ PA)
{
    __shared__ int ed[256];
    __shared__ float ev[256];
    int i = blockIdx.x, j = threadIdx.x;
    int lo = rowptr[i], hi = rowptr[i + 1];
    float a0 = 0.f, a1 = 0.f, a2 = 0.f, a3 = 0.f;
    for (int base = lo; base < hi; base += 256) {
        int cnt = min(hi - base, 256);
        __syncthreads();
        if (j < cnt) { ed[j] = sdst[base + j]; ev[j] = sval[base + j]; }
        __syncthreads();
        int q = 0;
        for (; q + 4 <= cnt; q += 4) {
            a0 += ev[q + 0] * bf2f(cur[(size_t)ed[q + 0] * 256 + j]);
            a1 += ev[q + 1] * bf2f(cur[(size_t)ed[q + 1] * 256 + j]);
            a2 += ev[q + 2] * bf2f(cur[(size_t)ed[q + 2] * 256 + j]);
            a3 += ev[q + 3] * bf2f(cur[(size_t)ed[q + 3] * 256 + j]);
        }
        for (; q < cnt; ++q)
            a0 += ev[q] * bf2f(cur[(size_t)ed[q] * 256 + j]);
    }
    float v = 0.5f * ((a0 + a1) + (a2 + a3));
    size_t idx = (size_t)i * 256 + j;
    nxt[idx] = f2bf(v);
    PA[idx] = f2bf(bf2f(PA[idx]) + v);
}

// ---------------- diagnostic stamps ----------------
__global__ void k_stamp(float* __restrict__ out, float c0, float c1, float c2)
{
    if (c0 != 0.f) out[0] = c0;
    if (c1 != 0.f) out[1] = c1;
    if (c2 != 0.f) out[2] = c2;
}

extern "C" void kernel_launch(void* const* d_in, const int* in_sizes, int n_in,
                              void* d_out, int out_size, void* d_ws, size_t ws_size,
                              hipStream_t stream)
{
    const float* X1   = (const float*)d_in[0];
    const float* X2   = (const float*)d_in[1];
    const int*   esrc = (const int*)d_in[2];
    const int*   edst = (const int*)d_in[3];
    const float* eval = (const float*)d_in[4];
    const float* W1   = (const float*)d_in[5];
    const float* b1   = (const float*)d_in[6];
    const float* W2   = (const float*)d_in[7];
    const float* b2   = (const float*)d_in[8];

    float* out_zm1 = (float*)d_out;
    float* out_zm2 = out_zm1 + (size_t)N_NODES * 256;
    float* out_hm  = out_zm2 + (size_t)N_NODES * 256;

    // ---- workspace carve (~60.9 MB) ----
    char* w = (char*)d_ws;
    unsigned short* PAb   = (unsigned short*)w; w += 25600000;   // Zb2, then ZM, then part_alpha
    unsigned short* curA  = (unsigned short*)w; w += 25600000;   // Zb1, then ZM ping buffer
    int* sdst             = (int*)w;            w += 3200000;
    float* sval           = (float*)w;          w += 3200000;
    int* counts           = (int*)w;            w += 200192;
    int* rowptr           = (int*)w;            w += 200192;
    int* cursor           = (int*)w;            w += 200192;
    float* G1             = (float*)w;          w += 262144;
    float* G2             = (float*)w;          w += 262144;
    float* Emat           = (float*)w;          w += 262144;
    float* SMh            = (float*)w;          w += 262144;
    float* S              = (float*)w;          w += 262144;
    float* P2             = (float*)w;          w += 262144;
    float* P3             = (float*)w;          w += 262144;
    float* rs             = (float*)w;          w += 1024;
    float* cs             = (float*)w;          w += 1024;
    float* gmax           = (float*)w;          w += 256;
    unsigned short* Wt1   = (unsigned short*)w; w += 393216;
    unsigned short* Wt2   = (unsigned short*)w; w += 262144;
    unsigned short* St    = (unsigned short*)w; w += 131072;
    size_t ws_need = (size_t)(w - (char*)d_ws);

    unsigned short* curB  = (unsigned short*)out_hm;   // dead until k_hm

    bool sizes_ok = (n_in == 9)
        && in_sizes[0] == 38400000 && in_sizes[1] == 25600000
        && in_sizes[2] == 800000 && in_sizes[3] == 800000 && in_sizes[4] == 800000
        && in_sizes[5] == 196608 && in_sizes[6] == 256
        && in_sizes[7] == 131072 && in_sizes[8] == 256;
    float c0 = (n_in != 9) ? 1000.f : 0.f;
    float c1 = (!sizes_ok && n_in == 9) ? 2000.f : 0.f;
    float c2 = (ws_size < ws_need) ? (4000.f + (float)(ws_size / 1000000ull)) : 0.f;

    // 0) weights -> bf16 transposed
    k_wt<<<768, 256, 0, stream>>>(W1, Wt1, 768);
    k_wt<<<512, 256, 0, stream>>>(W2, Wt2, 512);

    // 1) ZM1/ZM2 via MFMA, dual fp32+bf16 store (Zb1->curA, Zb2->PAb)
    k_gemm_mfma<<<(N_NODES + 63) / 64, 256, 0, stream>>>(X1, Wt1, b1, out_zm1, curA, N_NODES, 768);
    k_gemm_mfma<<<(N_NODES + 63) / 64, 256, 0, stream>>>(X2, Wt2, b2, out_zm2, PAb, N_NODES, 512);

    // 2) both Grams from bf16 in one dispatch, then the two softmax chains
    hipMemsetAsync(SMh, 0, 262144, stream);
    hipMemsetAsync(G1, 0, 262144, stream);
    hipMemsetAsync(G2, 0, 262144, stream);
    k_gram_mfma<<<dim3(2, 49, 2), 512, 0, stream>>>(curA, PAb, G1, G2, N_NODES);
    k_max<<<1, 256, 0, stream>>>(G1, gmax);
    k_exp<<<256, 256, 0, stream>>>(G1, gmax, Emat);
    k_rowsum<<<256, 256, 0, stream>>>(Emat, rs);
    k_colsum<<<1, 256, 0, stream>>>(Emat, cs);
    k_smacc<<<256, 256, 0, stream>>>(Emat, rs, cs, SMh);
    k_max<<<1, 256, 0, stream>>>(G2, gmax);
    k_exp<<<256, 256, 0, stream>>>(G2, gmax, Emat);
    k_rowsum<<<256, 256, 0, stream>>>(Emat, rs);
    k_colsum<<<1, 256, 0, stream>>>(Emat, cs);
    k_smacc<<<256, 256, 0, stream>>>(Emat, rs, cs, SMh);

    // 3) ZM: in-place average of Zb1 (curA) and Zb2 (PAb)
    k_zm<<<6250, 256, 0, stream>>>(curA, PAb);

    // 4) CSR by src
    hipMemsetAsync(counts, 0, 200192, stream);
    k_hist<<<NE / 256, 256, 0, stream>>>(esrc, counts);
    k_scan<<<1, 256, 0, stream>>>(counts, rowptr, cursor);
    k_scatter<<<NE / 256, 256, 0, stream>>>(esrc, edst, eval, cursor, sdst, sval);

    // 5) 4 propagation layers (curB parked in out_hm region)
    k_spmm<<<N_NODES, 256, 0, stream>>>(rowptr, sdst, sval, curA, curB, PAb);
    k_spmm<<<N_NODES, 256, 0, stream>>>(rowptr, sdst, sval, curB, curA, PAb);
    k_spmm<<<N_NODES, 256, 0, stream>>>(rowptr, sdst, sval, curA, curB, PAb);
    k_spmm<<<N_NODES, 256, 0, stream>>>(rowptr, sdst, sval, curB, curA, PAb);

    // 6) S = I + B + B^2 + B^3, then St = bf16(S^T)
    k_sinit<<<256, 256, 0, stream>>>(SMh, S);
    k_sgemm<<<256, 256, 0, stream>>>(SMh, SMh, P2, S);
    k_sgemm<<<256, 256, 0, stream>>>(P2, SMh, P3, S);
    k_st<<<256, 256, 0, stream>>>(S, St);

    // 7) HM = l2norm(PA @ S) via MFMA
    k_hm_mfma<<<(N_NODES + 63) / 64, 256, 0, stream>>>(PAb, St, out_hm, N_NODES);

    // 8) diagnostic stamps
    k_stamp<<<1, 1, 0, stream>>>(out_zm1, c0, c1, c2);
}

// Round 11
// 899.495 us; speedup vs baseline: 2.1088x; 1.1348x over previous
//
#include <hip/hip_runtime.h>
#include <hip/hip_bf16.h>

#define N_NODES 50000
#define NE      800000

typedef __attribute__((ext_vector_type(4))) float f32x4;
typedef __attribute__((ext_vector_type(8))) short s16x8;
typedef __attribute__((ext_vector_type(8))) unsigned short u16x8;

__device__ __forceinline__ float bf2f(unsigned short u) {
    union { unsigned int i; float f; } v; v.i = ((unsigned int)u) << 16; return v.f;
}
__device__ __forceinline__ unsigned short f2bf(float f) {
    union { unsigned int i; float f; } v; v.f = f;
    unsigned int x = v.i;
    return (unsigned short)((x + 0x7fffu + ((x >> 16) & 1u)) >> 16);  // RNE
}

// ---------------- weights: W fp32 (K,256) C-order -> Wt bf16 [256][K] ----------------
__global__ void k_wt(const float* __restrict__ W, unsigned short* __restrict__ Wt, int K)
{
    int idx = blockIdx.x * 256 + threadIdx.x;          // = j*K + k
    int j = idx / K, k = idx - j * K;
    Wt[idx] = f2bf(W[(size_t)k * 256 + j]);
}

// ---------------- S fp32 [256][256] -> St bf16 transposed ----------------
__global__ void k_st(const float* __restrict__ S, unsigned short* __restrict__ St)
{
    int k = blockIdx.x, j = threadIdx.x;
    St[j * 256 + k] = f2bf(S[k * 256 + j]);
}

// ---------------- GEMM + bias + row l2norm, bf16 MFMA; 128x256 tile, 8 waves ----------------
__global__ __launch_bounds__(512) void k_gemm_mfma(
    const float* __restrict__ X, const unsigned short* __restrict__ Wt,
    const float* __restrict__ bias, float* __restrict__ out,
    unsigned short* __restrict__ Zb, int M, int K)
{
    __shared__ unsigned short Alds[128][72];
    __shared__ unsigned short Blds[256][72];
    const int tid = threadIdx.x;
    const int m0 = blockIdx.x * 128;
    const int wave = tid >> 6, lane = tid & 63;
    const int l15 = lane & 15, lg = lane >> 4;

    f32x4 acc[16];
    for (int i = 0; i < 16; ++i) acc[i] = (f32x4)0.0f;

    for (int k0 = 0; k0 < K; k0 += 64) {
        // A tile: 128 rows x 64 cols, fp32 -> bf16
        for (int p = 0; p < 4; ++p) {
            int idx = tid + p * 512;          // 2048 float4 = 128 rows x 16
            int r = idx >> 4, c4 = idx & 15;
            int row = m0 + r;
            float4 v = make_float4(0.f, 0.f, 0.f, 0.f);
            if (row < M) v = *(const float4*)(X + (size_t)row * K + k0 + c4 * 4);
            unsigned short* d = &Alds[r][c4 * 4];
            d[0] = f2bf(v.x); d[1] = f2bf(v.y); d[2] = f2bf(v.z); d[3] = f2bf(v.w);
        }
        // B tile: 256 j x 64 k bf16
        for (int p = 0; p < 4; ++p) {
            int idx = tid + p * 512;          // 2048 u16x8
            int j = idx >> 3, k8 = idx & 7;
            *(u16x8*)&Blds[j][k8 * 8] = *(const u16x8*)(Wt + (size_t)j * K + k0 + k8 * 8);
        }
        __syncthreads();
        for (int kk = 0; kk < 2; ++kk) {
            s16x8 a = *(const s16x8*)&Alds[wave * 16 + l15][kk * 32 + lg * 8];
            for (int nt = 0; nt < 16; ++nt) {
                s16x8 b = *(const s16x8*)&Blds[nt * 16 + l15][kk * 32 + lg * 8];
                acc[nt] = __builtin_amdgcn_mfma_f32_16x16x32_bf16(a, b, acc[nt], 0, 0, 0);
            }
        }
        __syncthreads();
    }

    float sumsq[4] = {0.f, 0.f, 0.f, 0.f};
    for (int nt = 0; nt < 16; ++nt) {
        float bj = bias[nt * 16 + l15];
        for (int r = 0; r < 4; ++r) {
            float v = acc[nt][r] + bj;
            acc[nt][r] = v;
            sumsq[r] += v * v;
        }
    }
    for (int r = 0; r < 4; ++r) {
        float s = sumsq[r];
        s += __shfl_xor(s, 1); s += __shfl_xor(s, 2);
        s += __shfl_xor(s, 4); s += __shfl_xor(s, 8);
        sumsq[r] = 1.0f / fmaxf(sqrtf(s), 1e-12f);
    }
    for (int r = 0; r < 4; ++r) {
        int row = m0 + wave * 16 + lg * 4 + r;
        if (row < M) {
            for (int nt = 0; nt < 16; ++nt) {
                float v = acc[nt][r] * sumsq[r];
                out[(size_t)row * 256 + nt * 16 + l15] = v;
                Zb[(size_t)row * 256 + nt * 16 + l15] = f2bf(v);
            }
        }
    }
}

// ---------------- Gram via MFMA: bf16 source, 128-row slabs, 8-wave blocks ----------------
__global__ __launch_bounds__(512) void k_gram_mfma(
    const unsigned short* __restrict__ Zb1, const unsigned short* __restrict__ Zb2,
    float* __restrict__ G1, float* __restrict__ G2, int M)
{
    __shared__ unsigned short Zt[256][72];
    const unsigned short* Z = blockIdx.z ? Zb2 : Zb1;
    float* G = blockIdx.z ? G2 : G1;
    const int tid = threadIdx.x;
    const int ib = blockIdx.x;
    const int wave = tid >> 6, lane = tid & 63;
    const int l15 = lane & 15, lg = lane >> 4;
    const int TC = (M + 63) >> 6;                 // 782
    const int c0 = blockIdx.y * 16;
    const int c1 = min(c0 + 16, TC);

    const int ja = ib * 128 + wave * 16 + l15;
    const int sa = ((ja >> 2) & 7) << 3;

    f32x4 acc[16];
    for (int i = 0; i < 16; ++i) acc[i] = (f32x4)0.0f;

    for (int ch = c0; ch < c1; ++ch) {
        int base = ch * 64;
        __syncthreads();
        for (int p = 0; p < 4; ++p) {
            int idx = tid + p * 512;              // 2048 u16x8 = 64 m x 32 c8
            int m = idx >> 5, c8 = idx & 31;
            int row = base + m;
            u16x8 v = (u16x8)0;
            if (row < M) v = *(const u16x8*)(Z + (size_t)row * 256 + c8 * 8);
            for (int q = 0; q < 8; ++q) {
                int f = c8 * 8 + q;
                int cs = m ^ (((f >> 2) & 7) << 3);
                Zt[f][cs] = v[q];
            }
        }
        __syncthreads();
        for (int kk = 0; kk < 2; ++kk) {
            s16x8 a = *(const s16x8*)&Zt[ja][(kk * 32 + lg * 8) ^ sa];
            for (int nt = 0; nt < 16; ++nt) {
                int jb = nt * 16 + l15;
                int sb = ((jb >> 2) & 7) << 3;
                s16x8 b = *(const s16x8*)&Zt[jb][(kk * 32 + lg * 8) ^ sb];
                acc[nt] = __builtin_amdgcn_mfma_f32_16x16x32_bf16(a, b, acc[nt], 0, 0, 0);
            }
        }
    }
    for (int nt = 0; nt < 16; ++nt)
        for (int r = 0; r < 4; ++r)
            atomicAdd(&G[(ib * 128 + wave * 16 + lg * 4 + r) * 256 + nt * 16 + l15], acc[nt][r]);
}

// ---------------- HM = l2norm(PA @ S) via MFMA; 128x256 tile, 8 waves ----------------
__global__ __launch_bounds__(512) void k_hm_mfma(const unsigned short* __restrict__ PA,
                                                 const unsigned short* __restrict__ St,
                                                 float* __restrict__ out, int M)
{
    __shared__ unsigned short Alds[128][72];
    __shared__ unsigned short Blds[256][72];
    const int tid = threadIdx.x;
    const int m0 = blockIdx.x * 128;
    const int wave = tid >> 6, lane = tid & 63;
    const int l15 = lane & 15, lg = lane >> 4;

    f32x4 acc[16];
    for (int i = 0; i < 16; ++i) acc[i] = (f32x4)0.0f;

    for (int k0 = 0; k0 < 256; k0 += 64) {
        for (int p = 0; p < 2; ++p) {
            int idx = tid + p * 512;          // 1024 u16x8 = 128 rows x 8
            int r = idx >> 3, k8 = idx & 7;
            int row = m0 + r;
            u16x8 v = (u16x8)0;
            if (row < M) v = *(const u16x8*)(PA + (size_t)row * 256 + k0 + k8 * 8);
            *(u16x8*)&Alds[r][k8 * 8] = v;
        }
        for (int p = 0; p < 4; ++p) {
            int idx = tid + p * 512;
            int j = idx >> 3, k8 = idx & 7;
            *(u16x8*)&Blds[j][k8 * 8] = *(const u16x8*)(St + (size_t)j * 256 + k0 + k8 * 8);
        }
        __syncthreads();
        for (int kk = 0; kk < 2; ++kk) {
            s16x8 a = *(const s16x8*)&Alds[wave * 16 + l15][kk * 32 + lg * 8];
            for (int nt = 0; nt < 16; ++nt) {
                s16x8 b = *(const s16x8*)&Blds[nt * 16 + l15][kk * 32 + lg * 8];
                acc[nt] = __builtin_amdgcn_mfma_f32_16x16x32_bf16(a, b, acc[nt], 0, 0, 0);
            }
        }
        __syncthreads();
    }

    float sumsq[4] = {0.f, 0.f, 0.f, 0.f};
    for (int nt = 0; nt < 16; ++nt)
        for (int r = 0; r < 4; ++r)
            sumsq[r] += acc[nt][r] * acc[nt][r];
    for (int r = 0; r < 4; ++r) {
        float s = sumsq[r];
        s += __shfl_xor(s, 1); s += __shfl_xor(s, 2);
        s += __shfl_xor(s, 4); s += __shfl_xor(s, 8);
        sumsq[r] = 1.0f / fmaxf(sqrtf(s), 1e-12f);
    }
    for (int r = 0; r < 4; ++r) {
        int row = m0 + wave * 16 + lg * 4 + r;
        if (row < M) {
            for (int nt = 0; nt < 16; ++nt)
                out[(size_t)row * 256 + nt * 16 + l15] = acc[nt][r] * sumsq[r];
        }
    }
}

// ---------------- fused softmax helpers (batched over both matrices) ----------------
__global__ __launch_bounds__(256) void k_max2(const float* __restrict__ G1, const float* __restrict__ G2,
                                              float* __restrict__ gmax)
{
    const float* G = blockIdx.x ? G2 : G1;
    float m = -1e30f;
    for (int i = threadIdx.x; i < 65536; i += 256) m = fmaxf(m, G[i]);
    for (int s = 1; s < 64; s <<= 1) m = fmaxf(m, __shfl_xor(m, s));
    __shared__ float wm[4];
    if ((threadIdx.x & 63) == 0) wm[threadIdx.x >> 6] = m;
    __syncthreads();
    if (threadIdx.x == 0) gmax[blockIdx.x] = fmaxf(fmaxf(wm[0], wm[1]), fmaxf(wm[2], wm[3]));
}

// exp + rowsum fused: block (i, z)
__global__ __launch_bounds__(256) void k_exprow(const float* __restrict__ G1, const float* __restrict__ G2,
                                                const float* __restrict__ gmax,
                                                float* __restrict__ E1, float* __restrict__ E2,
                                                float* __restrict__ rs)
{
    const float inv_sqrt_n = 4.4721359549995794e-3f;
    int i = blockIdx.x, z = blockIdx.y, j = threadIdx.x;
    const float* G = z ? G2 : G1;
    float* E = z ? E2 : E1;
    float e = expf((G[i * 256 + j] - gmax[z]) * inv_sqrt_n);
    E[i * 256 + j] = e;
    float v = e;
    for (int m = 1; m < 64; m <<= 1) v += __shfl_xor(v, m);
    __shared__ float wm[4];
    if ((j & 63) == 0) wm[j >> 6] = v;
    __syncthreads();
    if (j == 0) rs[z * 256 + i] = wm[0] + wm[1] + wm[2] + wm[3];
}

// colsum partials: block (b, z) covers rows b*32..b*32+31
__global__ __launch_bounds__(256) void k_colsum(const float* __restrict__ E1, const float* __restrict__ E2,
                                                float* __restrict__ cs)
{
    int b = blockIdx.x, z = blockIdx.y, j = threadIdx.x;
    const float* E = z ? E2 : E1;
    float a = 0.f;
    for (int i = b * 32; i < b * 32 + 32; ++i) a += E[i * 256 + j];
    atomicAdd(&cs[z * 256 + j], a);
}

// SMh = 0.25*(E1/(sqrt(rs1)sqrt(cs1)) + E2/(sqrt(rs2)sqrt(cs2)))
__global__ __launch_bounds__(256) void k_smacc(const float* __restrict__ E1, const float* __restrict__ E2,
                                               const float* __restrict__ rs, const float* __restrict__ cs,
                                               float* __restrict__ SMh)
{
    int i = blockIdx.x, j = threadIdx.x;
    float v1 = E1[i * 256 + j] * rsqrtf(rs[i] + 1e-10f) * rsqrtf(cs[j] + 1e-10f);
    float v2 = E2[i * 256 + j] * rsqrtf(rs[256 + i] + 1e-10f) * rsqrtf(cs[256 + j] + 1e-10f);
    SMh[i * 256 + j] = 0.25f * (v1 + v2);
}

__global__ void k_sinit(const float* __restrict__ SMh, float* __restrict__ S)
{
    int i = blockIdx.x, j = threadIdx.x;
    S[i * 256 + j] = SMh[i * 256 + j] + (i == j ? 1.0f : 0.0f);
}

__global__ __launch_bounds__(256) void k_sgemm(const float* __restrict__ P, const float* __restrict__ SMh,
                                               float* __restrict__ Pn, float* __restrict__ S)
{
    __shared__ float pr[256];
    int i = blockIdx.x, j = threadIdx.x;
    pr[j] = P[i * 256 + j];
    __syncthreads();
    float a = 0.f;
    for (int k = 0; k < 256; ++k) a += pr[k] * SMh[k * 256 + j];
    Pn[i * 256 + j] = a;
    S[i * 256 + j] += a;
}

// ---------------- ZM: in-place average of the two bf16 copies ----------------
__global__ void k_zm(unsigned short* __restrict__ A, unsigned short* __restrict__ B)
{
    size_t i = ((size_t)blockIdx.x * 256 + threadIdx.x) * 8;
    u16x8 a = *(const u16x8*)(A + i), b = *(const u16x8*)(B + i);
    u16x8 c;
    for (int q = 0; q < 8; ++q) c[q] = f2bf(0.5f * (bf2f(a[q]) + bf2f(b[q])));
    *(u16x8*)(A + i) = c;
    *(u16x8*)(B + i) = c;
}

// ---------------- CSR build ----------------
__global__ void k_hist(const int* __restrict__ src, int* __restrict__ counts)
{
    int e = blockIdx.x * 256 + threadIdx.x;
    atomicAdd(&counts[src[e]], 1);
}

__global__ __launch_bounds__(256) void k_scan(const int* __restrict__ counts,
                                              int* __restrict__ rowptr, int* __restrict__ cursor)
{
    __shared__ int sums[256];
    int t = threadIdx.x;
    const int CH = 196;
    int lo = t * CH, hi = min(lo + CH, N_NODES);
    int s = 0;
    for (int i = lo; i < hi; ++i) s += counts[i];
    sums[t] = s;
    __syncthreads();
    if (t == 0) {
        int run = 0;
        for (int q = 0; q < 256; ++q) { int tmp = sums[q]; sums[q] = run; run += tmp; }
        rowptr[N_NODES] = run;
    }
    __syncthreads();
    int run = sums[t];
    for (int i = lo; i < hi; ++i) { rowptr[i] = run; cursor[i] = run; run += counts[i]; }
}

__global__ void k_scatter(const int* __restrict__ src, const int* __restrict__ dst,
                          const float* __restrict__ val, int* __restrict__ cursor,
                          int* __restrict__ sdst, float* __restrict__ sval)
{
    int e = blockIdx.x * 256 + threadIdx.x;
    int s = src[e];
    int pos = atomicAdd(&cursor[s], 1);
    sdst[pos] = dst[e];
    sval[pos] = val[e];
}

// ---------------- SpMM layer: nxt = 0.5 * A @ cur ; PA += nxt (bf16, unroll-4 ILP) ----------------
__global__ __launch_bounds__(256) void k_spmm(const int* __restrict__ rowptr, const int* __restrict__ sdst,
                                              const float* __restrict__ sval,
                                              const unsigned short* __restrict__ cur,
                                              unsigned short* __restrict__ nxt, unsigned short* __restrict__ PA)
{
    __shared__ int ed[256];
    __shared__ float ev[256];
    int i = blockIdx.x, j = threadIdx.x;
    int lo = rowptr[i], hi = rowptr[i + 1];
    float a0 = 0.f, a1 = 0.f, a2 = 0.f, a3 = 0.f;
    for (int base = lo; base < hi; base += 256) {
        int cnt = min(hi - base, 256);
        __syncthreads();
        if (j < cnt) { ed[j] = sdst[base + j]; ev[j] = sval[base + j]; }
        __syncthreads();
        int q = 0;
        for (; q + 4 <= cnt; q += 4) {
            a0 += ev[q + 0] * bf2f(cur[(size_t)ed[q + 0] * 256 + j]);
            a1 += ev[q + 1] * bf2f(cur[(size_t)ed[q + 1] * 256 + j]);
            a2 += ev[q + 2] * bf2f(cur[(size_t)ed[q + 2] * 256 + j]);
            a3 += ev[q + 3] * bf2f(cur[(size_t)ed[q + 3] * 256 + j]);
        }
        for (; q < cnt; ++q)
            a0 += ev[q] * bf2f(cur[(size_t)ed[q] * 256 + j]);
    }
    float v = 0.5f * ((a0 + a1) + (a2 + a3));
    size_t idx = (size_t)i * 256 + j;
    nxt[idx] = f2bf(v);
    PA[idx] = f2bf(bf2f(PA[idx]) + v);
}

// ---------------- diagnostic stamps ----------------
__global__ void k_stamp(float* __restrict__ out, float c0, float c1, float c2)
{
    if (c0 != 0.f) out[0] = c0;
    if (c1 != 0.f) out[1] = c1;
    if (c2 != 0.f) out[2] = c2;
}

extern "C" void kernel_launch(void* const* d_in, const int* in_sizes, int n_in,
                              void* d_out, int out_size, void* d_ws, size_t ws_size,
                              hipStream_t stream)
{
    const float* X1   = (const float*)d_in[0];
    const float* X2   = (const float*)d_in[1];
    const int*   esrc = (const int*)d_in[2];
    const int*   edst = (const int*)d_in[3];
    const float* eval = (const float*)d_in[4];
    const float* W1   = (const float*)d_in[5];
    const float* b1   = (const float*)d_in[6];
    const float* W2   = (const float*)d_in[7];
    const float* b2   = (const float*)d_in[8];

    float* out_zm1 = (float*)d_out;
    float* out_zm2 = out_zm1 + (size_t)N_NODES * 256;
    float* out_hm  = out_zm2 + (size_t)N_NODES * 256;

    // ---- workspace carve (~61.2 MB) ----
    char* w = (char*)d_ws;
    unsigned short* PAb   = (unsigned short*)w; w += 25600000;   // Zb2 -> ZM -> part_alpha
    unsigned short* curA  = (unsigned short*)w; w += 25600000;   // Zb1 -> ZM ping
    int* sdst             = (int*)w;            w += 3200000;
    float* sval           = (float*)w;          w += 3200000;
    int* counts           = (int*)w;            w += 200192;
    int* rowptr           = (int*)w;            w += 200192;
    int* cursor           = (int*)w;            w += 200192;
    float* G1             = (float*)w;          w += 262144;
    float* G2             = (float*)w;          w += 262144;
    float* E1             = (float*)w;          w += 262144;
    float* E2             = (float*)w;          w += 262144;
    float* SMh            = (float*)w;          w += 262144;
    float* S              = (float*)w;          w += 262144;
    float* P2             = (float*)w;          w += 262144;
    float* P3             = (float*)w;          w += 262144;
    float* rs             = (float*)w;          w += 2048;
    float* cs             = (float*)w;          w += 2048;
    float* gmax           = (float*)w;          w += 256;
    unsigned short* Wt1   = (unsigned short*)w; w += 393216;
    unsigned short* Wt2   = (unsigned short*)w; w += 262144;
    unsigned short* St    = (unsigned short*)w; w += 131072;
    size_t ws_need = (size_t)(w - (char*)d_ws);

    unsigned short* curB  = (unsigned short*)out_hm;   // dead until k_hm

    bool sizes_ok = (n_in == 9)
        && in_sizes[0] == 38400000 && in_sizes[1] == 25600000
        && in_sizes[2] == 800000 && in_sizes[3] == 800000 && in_sizes[4] == 800000
        && in_sizes[5] == 196608 && in_sizes[6] == 256
        && in_sizes[7] == 131072 && in_sizes[8] == 256;
    float c0 = (n_in != 9) ? 1000.f : 0.f;
    float c1 = (!sizes_ok && n_in == 9) ? 2000.f : 0.f;
    float c2 = (ws_size < ws_need) ? (4000.f + (float)(ws_size / 1000000ull)) : 0.f;

    // 0) weights -> bf16 transposed
    k_wt<<<768, 256, 0, stream>>>(W1, Wt1, 768);
    k_wt<<<512, 256, 0, stream>>>(W2, Wt2, 512);

    // 1) ZM1/ZM2 via MFMA 128-row tiles, dual fp32+bf16 store
    k_gemm_mfma<<<(N_NODES + 127) / 128, 512, 0, stream>>>(X1, Wt1, b1, out_zm1, curA, N_NODES, 768);
    k_gemm_mfma<<<(N_NODES + 127) / 128, 512, 0, stream>>>(X2, Wt2, b2, out_zm2, PAb, N_NODES, 512);

    // 2) Grams + fused/batched softmax chain
    hipMemsetAsync(G1, 0, 262144, stream);
    hipMemsetAsync(G2, 0, 262144, stream);
    hipMemsetAsync(cs, 0, 2048, stream);
    k_gram_mfma<<<dim3(2, 49, 2), 512, 0, stream>>>(curA, PAb, G1, G2, N_NODES);
    k_max2<<<2, 256, 0, stream>>>(G1, G2, gmax);
    k_exprow<<<dim3(256, 2), 256, 0, stream>>>(G1, G2, gmax, E1, E2, rs);
    k_colsum<<<dim3(8, 2), 256, 0, stream>>>(E1, E2, cs);
    k_smacc<<<256, 256, 0, stream>>>(E1, E2, rs, cs, SMh);

    // 3) ZM: in-place average of Zb1 (curA) and Zb2 (PAb)
    k_zm<<<6250, 256, 0, stream>>>(curA, PAb);

    // 4) CSR by src
    hipMemsetAsync(counts, 0, 200192, stream);
    k_hist<<<NE / 256, 256, 0, stream>>>(esrc, counts);
    k_scan<<<1, 256, 0, stream>>>(counts, rowptr, cursor);
    k_scatter<<<NE / 256, 256, 0, stream>>>(esrc, edst, eval, cursor, sdst, sval);

    // 5) 4 propagation layers (curB parked in out_hm region)
    k_spmm<<<N_NODES, 256, 0, stream>>>(rowptr, sdst, sval, curA, curB, PAb);
    k_spmm<<<N_NODES, 256, 0, stream>>>(rowptr, sdst, sval, curB, curA, PAb);
    k_spmm<<<N_NODES, 256, 0, stream>>>(rowptr, sdst, sval, curA, curB, PAb);
    k_spmm<<<N_NODES, 256, 0, stream>>>(rowptr, sdst, sval, curB, curA, PAb);

    // 6) S = I + B + B^2 + B^3, then St = bf16(S^T)
    k_sinit<<<256, 256, 0, stream>>>(SMh, S);
    k_sgemm<<<256, 256, 0, stream>>>(SMh, SMh, P2, S);
    k_sgemm<<<256, 256, 0, stream>>>(P2, SMh, P3, S);
    k_st<<<256, 256, 0, stream>>>(S, St);

    // 7) HM = l2norm(PA @ S) via MFMA 128-row tiles
    k_hm_mfma<<<(N_NODES + 127) / 128, 512, 0, stream>>>(PAb, St, out_hm, N_NODES);

    // 8) diagnostic stamps
    k_stamp<<<1, 1, 0, stream>>>(out_zm1, c0, c1, c2);
}

// Round 12
// 791.085 us; speedup vs baseline: 2.3978x; 1.1370x over previous
//
#include <hip/hip_runtime.h>
#include <hip/hip_bf16.h>

#define N_NODES 50000
#define NE      800000
#define NBLK_SCAN 196   // ceil(50000/256)

typedef __attribute__((ext_vector_type(4))) float f32x4;
typedef __attribute__((ext_vector_type(8))) short s16x8;
typedef __attribute__((ext_vector_type(8))) unsigned short u16x8;

__device__ __forceinline__ float bf2f(unsigned short u) {
    union { unsigned int i; float f; } v; v.i = ((unsigned int)u) << 16; return v.f;
}
__device__ __forceinline__ unsigned short f2bf(float f) {
    union { unsigned int i; float f; } v; v.f = f;
    unsigned int x = v.i;
    return (unsigned short)((x + 0x7fffu + ((x >> 16) & 1u)) >> 16);  // RNE
}

// ---------------- weights: W fp32 (K,256) C-order -> Wt bf16 [256][K] ----------------
__global__ void k_wt(const float* __restrict__ W, unsigned short* __restrict__ Wt, int K)
{
    int idx = blockIdx.x * 256 + threadIdx.x;          // = j*K + k
    int j = idx / K, k = idx - j * K;
    Wt[idx] = f2bf(W[(size_t)k * 256 + j]);
}

// ---------------- S fp32 [256][256] -> St bf16 transposed ----------------
__global__ void k_st(const float* __restrict__ S, unsigned short* __restrict__ St)
{
    int k = blockIdx.x, j = threadIdx.x;
    St[j * 256 + k] = f2bf(S[k * 256 + j]);
}

// ---------------- GEMM + bias + row l2norm, bf16 MFMA; 128x256 tile, 8 waves ----------------
__global__ __launch_bounds__(512) void k_gemm_mfma(
    const float* __restrict__ X, const unsigned short* __restrict__ Wt,
    const float* __restrict__ bias, float* __restrict__ out,
    unsigned short* __restrict__ Zb, int M, int K)
{
    __shared__ unsigned short Alds[128][72];
    __shared__ unsigned short Blds[256][72];
    const int tid = threadIdx.x;
    const int m0 = blockIdx.x * 128;
    const int wave = tid >> 6, lane = tid & 63;
    const int l15 = lane & 15, lg = lane >> 4;

    f32x4 acc[16];
    for (int i = 0; i < 16; ++i) acc[i] = (f32x4)0.0f;

    for (int k0 = 0; k0 < K; k0 += 64) {
        for (int p = 0; p < 4; ++p) {
            int idx = tid + p * 512;          // 2048 float4 = 128 rows x 16
            int r = idx >> 4, c4 = idx & 15;
            int row = m0 + r;
            float4 v = make_float4(0.f, 0.f, 0.f, 0.f);
            if (row < M) v = *(const float4*)(X + (size_t)row * K + k0 + c4 * 4);
            unsigned short* d = &Alds[r][c4 * 4];
            d[0] = f2bf(v.x); d[1] = f2bf(v.y); d[2] = f2bf(v.z); d[3] = f2bf(v.w);
        }
        for (int p = 0; p < 4; ++p) {
            int idx = tid + p * 512;          // 2048 u16x8
            int j = idx >> 3, k8 = idx & 7;
            *(u16x8*)&Blds[j][k8 * 8] = *(const u16x8*)(Wt + (size_t)j * K + k0 + k8 * 8);
        }
        __syncthreads();
        for (int kk = 0; kk < 2; ++kk) {
            s16x8 a = *(const s16x8*)&Alds[wave * 16 + l15][kk * 32 + lg * 8];
            for (int nt = 0; nt < 16; ++nt) {
                s16x8 b = *(const s16x8*)&Blds[nt * 16 + l15][kk * 32 + lg * 8];
                acc[nt] = __builtin_amdgcn_mfma_f32_16x16x32_bf16(a, b, acc[nt], 0, 0, 0);
            }
        }
        __syncthreads();
    }

    float sumsq[4] = {0.f, 0.f, 0.f, 0.f};
    for (int nt = 0; nt < 16; ++nt) {
        float bj = bias[nt * 16 + l15];
        for (int r = 0; r < 4; ++r) {
            float v = acc[nt][r] + bj;
            acc[nt][r] = v;
            sumsq[r] += v * v;
        }
    }
    for (int r = 0; r < 4; ++r) {
        float s = sumsq[r];
        s += __shfl_xor(s, 1); s += __shfl_xor(s, 2);
        s += __shfl_xor(s, 4); s += __shfl_xor(s, 8);
        sumsq[r] = 1.0f / fmaxf(sqrtf(s), 1e-12f);
    }
    for (int r = 0; r < 4; ++r) {
        int row = m0 + wave * 16 + lg * 4 + r;
        if (row < M) {
            for (int nt = 0; nt < 16; ++nt) {
                float v = acc[nt][r] * sumsq[r];
                out[(size_t)row * 256 + nt * 16 + l15] = v;
                Zb[(size_t)row * 256 + nt * 16 + l15] = f2bf(v);
            }
        }
    }
}

// ---------------- Gram via MFMA: bf16 source, 128-row slabs, 8-wave blocks ----------------
__global__ __launch_bounds__(512) void k_gram_mfma(
    const unsigned short* __restrict__ Zb1, const unsigned short* __restrict__ Zb2,
    float* __restrict__ G1, float* __restrict__ G2, int M)
{
    __shared__ unsigned short Zt[256][72];
    const unsigned short* Z = blockIdx.z ? Zb2 : Zb1;
    float* G = blockIdx.z ? G2 : G1;
    const int tid = threadIdx.x;
    const int ib = blockIdx.x;
    const int wave = tid >> 6, lane = tid & 63;
    const int l15 = lane & 15, lg = lane >> 4;
    const int TC = (M + 63) >> 6;                 // 782
    const int c0 = blockIdx.y * 16;
    const int c1 = min(c0 + 16, TC);

    const int ja = ib * 128 + wave * 16 + l15;
    const int sa = ((ja >> 2) & 7) << 3;

    f32x4 acc[16];
    for (int i = 0; i < 16; ++i) acc[i] = (f32x4)0.0f;

    for (int ch = c0; ch < c1; ++ch) {
        int base = ch * 64;
        __syncthreads();
        for (int p = 0; p < 4; ++p) {
            int idx = tid + p * 512;              // 2048 u16x8 = 64 m x 32 c8
            int m = idx >> 5, c8 = idx & 31;
            int row = base + m;
            u16x8 v = (u16x8)0;
            if (row < M) v = *(const u16x8*)(Z + (size_t)row * 256 + c8 * 8);
            for (int q = 0; q < 8; ++q) {
                int f = c8 * 8 + q;
                int cs = m ^ (((f >> 2) & 7) << 3);
                Zt[f][cs] = v[q];
            }
        }
        __syncthreads();
        for (int kk = 0; kk < 2; ++kk) {
            s16x8 a = *(const s16x8*)&Zt[ja][(kk * 32 + lg * 8) ^ sa];
            for (int nt = 0; nt < 16; ++nt) {
                int jb = nt * 16 + l15;
                int sb = ((jb >> 2) & 7) << 3;
                s16x8 b = *(const s16x8*)&Zt[jb][(kk * 32 + lg * 8) ^ sb];
                acc[nt] = __builtin_amdgcn_mfma_f32_16x16x32_bf16(a, b, acc[nt], 0, 0, 0);
            }
        }
    }
    for (int nt = 0; nt < 16; ++nt)
        for (int r = 0; r < 4; ++r)
            atomicAdd(&G[(ib * 128 + wave * 16 + lg * 4 + r) * 256 + nt * 16 + l15], acc[nt][r]);
}

// ---------------- HM = l2norm(PA @ S) via MFMA; 128x256 tile, 8 waves ----------------
__global__ __launch_bounds__(512) void k_hm_mfma(const unsigned short* __restrict__ PA,
                                                 const unsigned short* __restrict__ St,
                                                 float* __restrict__ out, int M)
{
    __shared__ unsigned short Alds[128][72];
    __shared__ unsigned short Blds[256][72];
    const int tid = threadIdx.x;
    const int m0 = blockIdx.x * 128;
    const int wave = tid >> 6, lane = tid & 63;
    const int l15 = lane & 15, lg = lane >> 4;

    f32x4 acc[16];
    for (int i = 0; i < 16; ++i) acc[i] = (f32x4)0.0f;

    for (int k0 = 0; k0 < 256; k0 += 64) {
        for (int p = 0; p < 2; ++p) {
            int idx = tid + p * 512;          // 1024 u16x8 = 128 rows x 8
            int r = idx >> 3, k8 = idx & 7;
            int row = m0 + r;
            u16x8 v = (u16x8)0;
            if (row < M) v = *(const u16x8*)(PA + (size_t)row * 256 + k0 + k8 * 8);
            *(u16x8*)&Alds[r][k8 * 8] = v;
        }
        for (int p = 0; p < 4; ++p) {
            int idx = tid + p * 512;
            int j = idx >> 3, k8 = idx & 7;
            *(u16x8*)&Blds[j][k8 * 8] = *(const u16x8*)(St + (size_t)j * 256 + k0 + k8 * 8);
        }
        __syncthreads();
        for (int kk = 0; kk < 2; ++kk) {
            s16x8 a = *(const s16x8*)&Alds[wave * 16 + l15][kk * 32 + lg * 8];
            for (int nt = 0; nt < 16; ++nt) {
                s16x8 b = *(const s16x8*)&Blds[nt * 16 + l15][kk * 32 + lg * 8];
                acc[nt] = __builtin_amdgcn_mfma_f32_16x16x32_bf16(a, b, acc[nt], 0, 0, 0);
            }
        }
        __syncthreads();
    }

    float sumsq[4] = {0.f, 0.f, 0.f, 0.f};
    for (int nt = 0; nt < 16; ++nt)
        for (int r = 0; r < 4; ++r)
            sumsq[r] += acc[nt][r] * acc[nt][r];
    for (int r = 0; r < 4; ++r) {
        float s = sumsq[r];
        s += __shfl_xor(s, 1); s += __shfl_xor(s, 2);
        s += __shfl_xor(s, 4); s += __shfl_xor(s, 8);
        sumsq[r] = 1.0f / fmaxf(sqrtf(s), 1e-12f);
    }
    for (int r = 0; r < 4; ++r) {
        int row = m0 + wave * 16 + lg * 4 + r;
        if (row < M) {
            for (int nt = 0; nt < 16; ++nt)
                out[(size_t)row * 256 + nt * 16 + l15] = acc[nt][r] * sumsq[r];
        }
    }
}

// ---------------- fused softmax helpers (batched over both matrices) ----------------
__global__ __launch_bounds__(256) void k_max2(const float* __restrict__ G1, const float* __restrict__ G2,
                                              float* __restrict__ gmax)
{
    const float* G = blockIdx.x ? G2 : G1;
    float m = -1e30f;
    for (int i = threadIdx.x; i < 65536; i += 256) m = fmaxf(m, G[i]);
    for (int s = 1; s < 64; s <<= 1) m = fmaxf(m, __shfl_xor(m, s));
    __shared__ float wm[4];
    if ((threadIdx.x & 63) == 0) wm[threadIdx.x >> 6] = m;
    __syncthreads();
    if (threadIdx.x == 0) gmax[blockIdx.x] = fmaxf(fmaxf(wm[0], wm[1]), fmaxf(wm[2], wm[3]));
}

__global__ __launch_bounds__(256) void k_exprow(const float* __restrict__ G1, const float* __restrict__ G2,
                                                const float* __restrict__ gmax,
                                                float* __restrict__ E1, float* __restrict__ E2,
                                                float* __restrict__ rs)
{
    const float inv_sqrt_n = 4.4721359549995794e-3f;
    int i = blockIdx.x, z = blockIdx.y, j = threadIdx.x;
    const float* G = z ? G2 : G1;
    float* E = z ? E2 : E1;
    float e = expf((G[i * 256 + j] - gmax[z]) * inv_sqrt_n);
    E[i * 256 + j] = e;
    float v = e;
    for (int m = 1; m < 64; m <<= 1) v += __shfl_xor(v, m);
    __shared__ float wm[4];
    if ((j & 63) == 0) wm[j >> 6] = v;
    __syncthreads();
    if (j == 0) rs[z * 256 + i] = wm[0] + wm[1] + wm[2] + wm[3];
}

__global__ __launch_bounds__(256) void k_colsum(const float* __restrict__ E1, const float* __restrict__ E2,
                                                float* __restrict__ cs)
{
    int b = blockIdx.x, z = blockIdx.y, j = threadIdx.x;
    const float* E = z ? E2 : E1;
    float a = 0.f;
    for (int i = b * 32; i < b * 32 + 32; ++i) a += E[i * 256 + j];
    atomicAdd(&cs[z * 256 + j], a);
}

__global__ __launch_bounds__(256) void k_smacc(const float* __restrict__ E1, const float* __restrict__ E2,
                                               const float* __restrict__ rs, const float* __restrict__ cs,
                                               float* __restrict__ SMh)
{
    int i = blockIdx.x, j = threadIdx.x;
    float v1 = E1[i * 256 + j] * rsqrtf(rs[i] + 1e-10f) * rsqrtf(cs[j] + 1e-10f);
    float v2 = E2[i * 256 + j] * rsqrtf(rs[256 + i] + 1e-10f) * rsqrtf(cs[256 + j] + 1e-10f);
    SMh[i * 256 + j] = 0.25f * (v1 + v2);
}

__global__ void k_sinit(const float* __restrict__ SMh, float* __restrict__ S)
{
    int i = blockIdx.x, j = threadIdx.x;
    S[i * 256 + j] = SMh[i * 256 + j] + (i == j ? 1.0f : 0.0f);
}

__global__ __launch_bounds__(256) void k_sgemm(const float* __restrict__ P, const float* __restrict__ SMh,
                                               float* __restrict__ Pn, float* __restrict__ S)
{
    __shared__ float pr[256];
    int i = blockIdx.x, j = threadIdx.x;
    pr[j] = P[i * 256 + j];
    __syncthreads();
    float a = 0.f;
    for (int k = 0; k < 256; ++k) a += pr[k] * SMh[k * 256 + j];
    Pn[i * 256 + j] = a;
    S[i * 256 + j] += a;
}

// ---------------- ZM: in-place average of the two bf16 copies ----------------
__global__ void k_zm(unsigned short* __restrict__ A, unsigned short* __restrict__ B)
{
    size_t i = ((size_t)blockIdx.x * 256 + threadIdx.x) * 8;
    u16x8 a = *(const u16x8*)(A + i), b = *(const u16x8*)(B + i);
    u16x8 c;
    for (int q = 0; q < 8; ++q) c[q] = f2bf(0.5f * (bf2f(a[q]) + bf2f(b[q])));
    *(u16x8*)(A + i) = c;
    *(u16x8*)(B + i) = c;
}

// ---------------- CSR build: hist + 3-phase parallel scan + scatter ----------------
__global__ void k_hist(const int* __restrict__ src, int* __restrict__ counts)
{
    int e = blockIdx.x * 256 + threadIdx.x;
    atomicAdd(&counts[src[e]], 1);
}

__global__ __launch_bounds__(256) void k_bsum(const int* __restrict__ counts, int* __restrict__ bsum)
{
    int i = blockIdx.x * 256 + threadIdx.x;
    int v = (i < N_NODES) ? counts[i] : 0;
    for (int m = 1; m < 64; m <<= 1) v += __shfl_xor(v, m);
    __shared__ int wm[4];
    if ((threadIdx.x & 63) == 0) wm[threadIdx.x >> 6] = v;
    __syncthreads();
    if (threadIdx.x == 0) bsum[blockIdx.x] = wm[0] + wm[1] + wm[2] + wm[3];
}

__global__ __launch_bounds__(256) void k_bscan(const int* __restrict__ bsum, int* __restrict__ boff,
                                               int* __restrict__ rowptr)
{
    __shared__ int tmp[256];
    int t = threadIdx.x;
    int v = (t < NBLK_SCAN) ? bsum[t] : 0;
    tmp[t] = v;
    __syncthreads();
    for (int off = 1; off < 256; off <<= 1) {
        int add = (t >= off) ? tmp[t - off] : 0;
        __syncthreads();
        tmp[t] += add;
        __syncthreads();
    }
    if (t < NBLK_SCAN) boff[t] = tmp[t] - v;     // exclusive block offset
    if (t == NBLK_SCAN - 1) rowptr[N_NODES] = tmp[t];
}

__global__ __launch_bounds__(256) void k_rowptr(const int* __restrict__ counts, const int* __restrict__ boff,
                                                int* __restrict__ rowptr, int* __restrict__ cursor)
{
    __shared__ int tmp[256];
    int b = blockIdx.x, t = threadIdx.x;
    int i = b * 256 + t;
    int v = (i < N_NODES) ? counts[i] : 0;
    tmp[t] = v;
    __syncthreads();
    for (int off = 1; off < 256; off <<= 1) {
        int add = (t >= off) ? tmp[t - off] : 0;
        __syncthreads();
        tmp[t] += add;
        __syncthreads();
    }
    int excl = tmp[t] - v + boff[b];
    if (i < N_NODES) { rowptr[i] = excl; cursor[i] = excl; }
}

__global__ void k_scatter(const int* __restrict__ src, const int* __restrict__ dst,
                          const float* __restrict__ val, int* __restrict__ cursor,
                          int* __restrict__ sdst, float* __restrict__ sval)
{
    int e = blockIdx.x * 256 + threadIdx.x;
    int s = src[e];
    int pos = atomicAdd(&cursor[s], 1);
    sdst[pos] = dst[e];
    sval[pos] = val[e];
}

// ---------------- SpMM layer: nxt = 0.5 * A @ cur ; PA += nxt (bf16, unroll-4 ILP) ----------------
__global__ __launch_bounds__(256) void k_spmm(const int* __restrict__ rowptr, const int* __restrict__ sdst,
                                              const float* __restrict__ sval,
                                              const unsigned short* __restrict__ cur,
                                              unsigned short* __restrict__ nxt, unsigned short* __restrict__ PA)
{
    __shared__ int ed[256];
    __shared__ float ev[256];
    int i = blockIdx.x, j = threadIdx.x;
    int lo = rowptr[i], hi = rowptr[i + 1];
    float a0 = 0.f, a1 = 0.f, a2 = 0.f, a3 = 0.f;
    for (int base = lo; base < hi; base += 256) {
        int cnt = min(hi - base, 256);
        __syncthreads();
        if (j < cnt) { ed[j] = sdst[base + j]; ev[j] = sval[base + j]; }
        __syncthreads();
        int q = 0;
        for (; q + 4 <= cnt; q += 4) {
            a0 += ev[q + 0] * bf2f(cur[(size_t)ed[q + 0] * 256 + j]);
            a1 += ev[q + 1] * bf2f(cur[(size_t)ed[q + 1] * 256 + j]);
            a2 += ev[q + 2] * bf2f(cur[(size_t)ed[q + 2] * 256 + j]);
            a3 += ev[q + 3] * bf2f(cur[(size_t)ed[q + 3] * 256 + j]);
        }
        for (; q < cnt; ++q)
            a0 += ev[q] * bf2f(cur[(size_t)ed[q] * 256 + j]);
    }
    float v = 0.5f * ((a0 + a1) + (a2 + a3));
    size_t idx = (size_t)i * 256 + j;
    nxt[idx] = f2bf(v);
    PA[idx] = f2bf(bf2f(PA[idx]) + v);
}

// ---------------- diagnostic stamps ----------------
__global__ void k_stamp(float* __restrict__ out, float c0, float c1, float c2)
{
    if (c0 != 0.f) out[0] = c0;
    if (c1 != 0.f) out[1] = c1;
    if (c2 != 0.f) out[2] = c2;
}

extern "C" void kernel_launch(void* const* d_in, const int* in_sizes, int n_in,
                              void* d_out, int out_size, void* d_ws, size_t ws_size,
                              hipStream_t stream)
{
    const float* X1   = (const float*)d_in[0];
    const float* X2   = (const float*)d_in[1];
    const int*   esrc = (const int*)d_in[2];
    const int*   edst = (const int*)d_in[3];
    const float* eval = (const float*)d_in[4];
    const float* W1   = (const float*)d_in[5];
    const float* b1   = (const float*)d_in[6];
    const float* W2   = (const float*)d_in[7];
    const float* b2   = (const float*)d_in[8];

    float* out_zm1 = (float*)d_out;
    float* out_zm2 = out_zm1 + (size_t)N_NODES * 256;
    float* out_hm  = out_zm2 + (size_t)N_NODES * 256;

    // ---- workspace carve (~61.2 MB) ----
    char* w = (char*)d_ws;
    unsigned short* PAb   = (unsigned short*)w; w += 25600000;   // Zb2 -> ZM -> part_alpha
    unsigned short* curA  = (unsigned short*)w; w += 25600000;   // Zb1 -> ZM ping
    int* sdst             = (int*)w;            w += 3200000;
    float* sval           = (float*)w;          w += 3200000;
    int* counts           = (int*)w;            w += 200192;
    int* rowptr           = (int*)w;            w += 200192;
    int* cursor           = (int*)w;            w += 200192;
    float* G1             = (float*)w;          w += 262144;
    float* G2             = (float*)w;          w += 262144;
    float* E1             = (float*)w;          w += 262144;
    float* E2             = (float*)w;          w += 262144;
    float* SMh            = (float*)w;          w += 262144;
    float* S              = (float*)w;          w += 262144;
    float* P2             = (float*)w;          w += 262144;
    float* P3             = (float*)w;          w += 262144;
    float* rs             = (float*)w;          w += 2048;
    float* cs             = (float*)w;          w += 2048;
    float* gmax           = (float*)w;          w += 256;
    int* bsum             = (int*)w;            w += 1024;
    int* boff             = (int*)w;            w += 1024;
    unsigned short* Wt1   = (unsigned short*)w; w += 393216;
    unsigned short* Wt2   = (unsigned short*)w; w += 262144;
    unsigned short* St    = (unsigned short*)w; w += 131072;
    size_t ws_need = (size_t)(w - (char*)d_ws);

    unsigned short* curB  = (unsigned short*)out_hm;   // dead until k_hm

    bool sizes_ok = (n_in == 9)
        && in_sizes[0] == 38400000 && in_sizes[1] == 25600000
        && in_sizes[2] == 800000 && in_sizes[3] == 800000 && in_sizes[4] == 800000
        && in_sizes[5] == 196608 && in_sizes[6] == 256
        && in_sizes[7] == 131072 && in_sizes[8] == 256;
    float c0 = (n_in != 9) ? 1000.f : 0.f;
    float c1 = (!sizes_ok && n_in == 9) ? 2000.f : 0.f;
    float c2 = (ws_size < ws_need) ? (4000.f + (float)(ws_size / 1000000ull)) : 0.f;

    // 0) weights -> bf16 transposed
    k_wt<<<768, 256, 0, stream>>>(W1, Wt1, 768);
    k_wt<<<512, 256, 0, stream>>>(W2, Wt2, 512);

    // 1) ZM1/ZM2 via MFMA 128-row tiles, dual fp32+bf16 store
    k_gemm_mfma<<<(N_NODES + 127) / 128, 512, 0, stream>>>(X1, Wt1, b1, out_zm1, curA, N_NODES, 768);
    k_gemm_mfma<<<(N_NODES + 127) / 128, 512, 0, stream>>>(X2, Wt2, b2, out_zm2, PAb, N_NODES, 512);

    // 2) Grams + fused/batched softmax chain
    hipMemsetAsync(G1, 0, 262144, stream);
    hipMemsetAsync(G2, 0, 262144, stream);
    hipMemsetAsync(cs, 0, 2048, stream);
    k_gram_mfma<<<dim3(2, 49, 2), 512, 0, stream>>>(curA, PAb, G1, G2, N_NODES);
    k_max2<<<2, 256, 0, stream>>>(G1, G2, gmax);
    k_exprow<<<dim3(256, 2), 256, 0, stream>>>(G1, G2, gmax, E1, E2, rs);
    k_colsum<<<dim3(8, 2), 256, 0, stream>>>(E1, E2, cs);
    k_smacc<<<256, 256, 0, stream>>>(E1, E2, rs, cs, SMh);

    // 3) ZM: in-place average of Zb1 (curA) and Zb2 (PAb)
    k_zm<<<6250, 256, 0, stream>>>(curA, PAb);

    // 4) CSR by src (parallel 3-phase scan)
    hipMemsetAsync(counts, 0, 200192, stream);
    k_hist<<<NE / 256, 256, 0, stream>>>(esrc, counts);
    k_bsum<<<NBLK_SCAN, 256, 0, stream>>>(counts, bsum);
    k_bscan<<<1, 256, 0, stream>>>(bsum, boff, rowptr);
    k_rowptr<<<NBLK_SCAN, 256, 0, stream>>>(counts, boff, rowptr, cursor);
    k_scatter<<<NE / 256, 256, 0, stream>>>(esrc, edst, eval, cursor, sdst, sval);

    // 5) 4 propagation layers (curB parked in out_hm region)
    k_spmm<<<N_NODES, 256, 0, stream>>>(rowptr, sdst, sval, curA, curB, PAb);
    k_spmm<<<N_NODES, 256, 0, stream>>>(rowptr, sdst, sval, curB, curA, PAb);
    k_spmm<<<N_NODES, 256, 0, stream>>>(rowptr, sdst, sval, curA, curB, PAb);
    k_spmm<<<N_NODES, 256, 0, stream>>>(rowptr, sdst, sval, curB, curA, PAb);

    // 6) S = I + B + B^2 + B^3, then St = bf16(S^T)
    k_sinit<<<256, 256, 0, stream>>>(SMh, S);
    k_sgemm<<<256, 256, 0, stream>>>(SMh, SMh, P2, S);
    k_sgemm<<<256, 256, 0, stream>>>(P2, SMh, P3, S);
    k_st<<<256, 256, 0, stream>>>(S, St);

    // 7) HM = l2norm(PA @ S) via MFMA 128-row tiles
    k_hm_mfma<<<(N_NODES + 127) / 128, 512, 0, stream>>>(PAb, St, out_hm, N_NODES);

    // 8) diagnostic stamps
    k_stamp<<<1, 1, 0, stream>>>(out_zm1, c0, c1, c2);
}

// Round 13
// 788.594 us; speedup vs baseline: 2.4054x; 1.0032x over previous
//
#include <hip/hip_runtime.h>
#include <hip/hip_bf16.h>

#define N_NODES 50000
#define NE      800000
#define NBLK_SCAN 196   // ceil(50000/256)

typedef __attribute__((ext_vector_type(4))) float f32x4;
typedef __attribute__((ext_vector_type(8))) short s16x8;
typedef __attribute__((ext_vector_type(8))) unsigned short u16x8;

__device__ __forceinline__ float bf2f(unsigned short u) {
    union { unsigned int i; float f; } v; v.i = ((unsigned int)u) << 16; return v.f;
}
__device__ __forceinline__ unsigned short f2bf(float f) {
    union { unsigned int i; float f; } v; v.f = f;
    unsigned int x = v.i;
    return (unsigned short)((x + 0x7fffu + ((x >> 16) & 1u)) >> 16);  // RNE
}

// ---------------- weights: W fp32 (K,256) C-order -> Wt bf16 [256][K] ----------------
__global__ void k_wt(const float* __restrict__ W, unsigned short* __restrict__ Wt, int K)
{
    int idx = blockIdx.x * 256 + threadIdx.x;          // = j*K + k
    int j = idx / K, k = idx - j * K;
    Wt[idx] = f2bf(W[(size_t)k * 256 + j]);
}

// ---------------- S fp32 [256][256] -> St bf16 transposed ----------------
__global__ void k_st(const float* __restrict__ S, unsigned short* __restrict__ St)
{
    int k = blockIdx.x, j = threadIdx.x;
    St[j * 256 + k] = f2bf(S[k * 256 + j]);
}

// ---------------- GEMM + bias + row l2norm, bf16 MFMA; 128x256 tile, 2x4 wave grid ----------------
__global__ __launch_bounds__(512) void k_gemm_mfma(
    const float* __restrict__ X, const unsigned short* __restrict__ Wt,
    const float* __restrict__ bias, float* __restrict__ out,
    unsigned short* __restrict__ Zb, int M, int K)
{
    __shared__ unsigned short Alds[128][72];
    __shared__ unsigned short Blds[256][72];
    __shared__ float part[4][136];
    const int tid = threadIdx.x;
    const int m0 = blockIdx.x * 128;
    const int wave = tid >> 6, lane = tid & 63;
    const int wr = wave >> 2, wc = wave & 3;
    const int l15 = lane & 15, lg = lane >> 4;

    f32x4 acc[4][4];
    for (int a = 0; a < 4; ++a) for (int b = 0; b < 4; ++b) acc[a][b] = (f32x4)0.0f;

    for (int k0 = 0; k0 < K; k0 += 64) {
        // A tile 128x64: fp32 -> bf16, packed ds_write_b64
        for (int p = 0; p < 4; ++p) {
            int idx = tid + p * 512;          // 2048 float4 = 128 rows x 16
            int r = idx >> 4, c4 = idx & 15;
            int row = m0 + r;
            float4 v = make_float4(0.f, 0.f, 0.f, 0.f);
            if (row < M) v = *(const float4*)(X + (size_t)row * K + k0 + c4 * 4);
            ushort4 pk;
            pk.x = f2bf(v.x); pk.y = f2bf(v.y); pk.z = f2bf(v.z); pk.w = f2bf(v.w);
            *(ushort4*)&Alds[r][c4 * 4] = pk;
        }
        // B tile 256x64 bf16
        for (int p = 0; p < 4; ++p) {
            int idx = tid + p * 512;          // 2048 u16x8
            int j = idx >> 3, k8 = idx & 7;
            *(u16x8*)&Blds[j][k8 * 8] = *(const u16x8*)(Wt + (size_t)j * K + k0 + k8 * 8);
        }
        __syncthreads();
        for (int kk = 0; kk < 2; ++kk) {
            s16x8 af[4], bfr[4];
            for (int mt = 0; mt < 4; ++mt)
                af[mt] = *(const s16x8*)&Alds[wr * 64 + mt * 16 + l15][kk * 32 + lg * 8];
            for (int nt = 0; nt < 4; ++nt)
                bfr[nt] = *(const s16x8*)&Blds[wc * 64 + nt * 16 + l15][kk * 32 + lg * 8];
            for (int mt = 0; mt < 4; ++mt)
                for (int nt = 0; nt < 4; ++nt)
                    acc[mt][nt] = __builtin_amdgcn_mfma_f32_16x16x32_bf16(af[mt], bfr[nt], acc[mt][nt], 0, 0, 0);
        }
        __syncthreads();
    }

    // bias + per-wave (64-col) sumsq partials, reduced over l15
    for (int mt = 0; mt < 4; ++mt) {
        for (int nt = 0; nt < 4; ++nt) {
            float bj = bias[wc * 64 + nt * 16 + l15];
            for (int r = 0; r < 4; ++r) acc[mt][nt][r] += bj;
        }
        for (int r = 0; r < 4; ++r) {
            float p = 0.f;
            for (int nt = 0; nt < 4; ++nt) p += acc[mt][nt][r] * acc[mt][nt][r];
            p += __shfl_xor(p, 1); p += __shfl_xor(p, 2);
            p += __shfl_xor(p, 4); p += __shfl_xor(p, 8);
            if (l15 == 0) part[wc][wr * 64 + mt * 16 + lg * 4 + r] = p;
        }
    }
    __syncthreads();
    for (int mt = 0; mt < 4; ++mt) {
        for (int r = 0; r < 4; ++r) {
            int rl = wr * 64 + mt * 16 + lg * 4 + r;
            float s = part[0][rl] + part[1][rl] + part[2][rl] + part[3][rl];
            float inv = 1.0f / fmaxf(sqrtf(s), 1e-12f);
            int row = m0 + rl;
            if (row < M) {
                for (int nt = 0; nt < 4; ++nt) {
                    float v = acc[mt][nt][r] * inv;
                    size_t o = (size_t)row * 256 + wc * 64 + nt * 16 + l15;
                    out[o] = v;
                    Zb[o] = f2bf(v);
                }
            }
        }
    }
}

// ---------------- Gram via MFMA: bf16 source, 128-row slabs, 8-wave blocks ----------------
__global__ __launch_bounds__(512) void k_gram_mfma(
    const unsigned short* __restrict__ Zb1, const unsigned short* __restrict__ Zb2,
    float* __restrict__ G1, float* __restrict__ G2, int M)
{
    __shared__ unsigned short Zt[256][72];
    const unsigned short* Z = blockIdx.z ? Zb2 : Zb1;
    float* G = blockIdx.z ? G2 : G1;
    const int tid = threadIdx.x;
    const int ib = blockIdx.x;
    const int wave = tid >> 6, lane = tid & 63;
    const int l15 = lane & 15, lg = lane >> 4;
    const int TC = (M + 63) >> 6;                 // 782
    const int c0 = blockIdx.y * 16;
    const int c1 = min(c0 + 16, TC);

    const int ja = ib * 128 + wave * 16 + l15;
    const int sa = ((ja >> 2) & 7) << 3;

    f32x4 acc[16];
    for (int i = 0; i < 16; ++i) acc[i] = (f32x4)0.0f;

    for (int ch = c0; ch < c1; ++ch) {
        int base = ch * 64;
        __syncthreads();
        for (int p = 0; p < 4; ++p) {
            int idx = tid + p * 512;              // 2048 u16x8 = 64 m x 32 c8
            int m = idx >> 5, c8 = idx & 31;
            int row = base + m;
            u16x8 v = (u16x8)0;
            if (row < M) v = *(const u16x8*)(Z + (size_t)row * 256 + c8 * 8);
            for (int q = 0; q < 8; ++q) {
                int f = c8 * 8 + q;
                int cs = m ^ (((f >> 2) & 7) << 3);
                Zt[f][cs] = v[q];
            }
        }
        __syncthreads();
        for (int kk = 0; kk < 2; ++kk) {
            s16x8 a = *(const s16x8*)&Zt[ja][(kk * 32 + lg * 8) ^ sa];
            for (int nt = 0; nt < 16; ++nt) {
                int jb = nt * 16 + l15;
                int sb = ((jb >> 2) & 7) << 3;
                s16x8 b = *(const s16x8*)&Zt[jb][(kk * 32 + lg * 8) ^ sb];
                acc[nt] = __builtin_amdgcn_mfma_f32_16x16x32_bf16(a, b, acc[nt], 0, 0, 0);
            }
        }
    }
    for (int nt = 0; nt < 16; ++nt)
        for (int r = 0; r < 4; ++r)
            atomicAdd(&G[(ib * 128 + wave * 16 + lg * 4 + r) * 256 + nt * 16 + l15], acc[nt][r]);
}

// ---------------- HM = l2norm(PA @ S) via MFMA; 128x256 tile, 2x4 wave grid ----------------
__global__ __launch_bounds__(512) void k_hm_mfma(const unsigned short* __restrict__ PA,
                                                 const unsigned short* __restrict__ St,
                                                 float* __restrict__ out, int M)
{
    __shared__ unsigned short Alds[128][72];
    __shared__ unsigned short Blds[256][72];
    __shared__ float part[4][136];
    const int tid = threadIdx.x;
    const int m0 = blockIdx.x * 128;
    const int wave = tid >> 6, lane = tid & 63;
    const int wr = wave >> 2, wc = wave & 3;
    const int l15 = lane & 15, lg = lane >> 4;

    f32x4 acc[4][4];
    for (int a = 0; a < 4; ++a) for (int b = 0; b < 4; ++b) acc[a][b] = (f32x4)0.0f;

    for (int k0 = 0; k0 < 256; k0 += 64) {
        for (int p = 0; p < 2; ++p) {
            int idx = tid + p * 512;          // 1024 u16x8 = 128 rows x 8
            int r = idx >> 3, k8 = idx & 7;
            int row = m0 + r;
            u16x8 v = (u16x8)0;
            if (row < M) v = *(const u16x8*)(PA + (size_t)row * 256 + k0 + k8 * 8);
            *(u16x8*)&Alds[r][k8 * 8] = v;
        }
        for (int p = 0; p < 4; ++p) {
            int idx = tid + p * 512;
            int j = idx >> 3, k8 = idx & 7;
            *(u16x8*)&Blds[j][k8 * 8] = *(const u16x8*)(St + (size_t)j * 256 + k0 + k8 * 8);
        }
        __syncthreads();
        for (int kk = 0; kk < 2; ++kk) {
            s16x8 af[4], bfr[4];
            for (int mt = 0; mt < 4; ++mt)
                af[mt] = *(const s16x8*)&Alds[wr * 64 + mt * 16 + l15][kk * 32 + lg * 8];
            for (int nt = 0; nt < 4; ++nt)
                bfr[nt] = *(const s16x8*)&Blds[wc * 64 + nt * 16 + l15][kk * 32 + lg * 8];
            for (int mt = 0; mt < 4; ++mt)
                for (int nt = 0; nt < 4; ++nt)
                    acc[mt][nt] = __builtin_amdgcn_mfma_f32_16x16x32_bf16(af[mt], bfr[nt], acc[mt][nt], 0, 0, 0);
        }
        __syncthreads();
    }

    for (int mt = 0; mt < 4; ++mt) {
        for (int r = 0; r < 4; ++r) {
            float p = 0.f;
            for (int nt = 0; nt < 4; ++nt) p += acc[mt][nt][r] * acc[mt][nt][r];
            p += __shfl_xor(p, 1); p += __shfl_xor(p, 2);
            p += __shfl_xor(p, 4); p += __shfl_xor(p, 8);
            if (l15 == 0) part[wc][wr * 64 + mt * 16 + lg * 4 + r] = p;
        }
    }
    __syncthreads();
    for (int mt = 0; mt < 4; ++mt) {
        for (int r = 0; r < 4; ++r) {
            int rl = wr * 64 + mt * 16 + lg * 4 + r;
            float s = part[0][rl] + part[1][rl] + part[2][rl] + part[3][rl];
            float inv = 1.0f / fmaxf(sqrtf(s), 1e-12f);
            int row = m0 + rl;
            if (row < M) {
                for (int nt = 0; nt < 4; ++nt)
                    out[(size_t)row * 256 + wc * 64 + nt * 16 + l15] = acc[mt][nt][r] * inv;
            }
        }
    }
}

// ---------------- fused softmax helpers (batched over both matrices) ----------------
__global__ __launch_bounds__(256) void k_max2(const float* __restrict__ G1, const float* __restrict__ G2,
                                              float* __restrict__ gmax)
{
    const float* G = blockIdx.x ? G2 : G1;
    float m = -1e30f;
    for (int i = threadIdx.x; i < 65536; i += 256) m = fmaxf(m, G[i]);
    for (int s = 1; s < 64; s <<= 1) m = fmaxf(m, __shfl_xor(m, s));
    __shared__ float wm[4];
    if ((threadIdx.x & 63) == 0) wm[threadIdx.x >> 6] = m;
    __syncthreads();
    if (threadIdx.x == 0) gmax[blockIdx.x] = fmaxf(fmaxf(wm[0], wm[1]), fmaxf(wm[2], wm[3]));
}

__global__ __launch_bounds__(256) void k_exprow(const float* __restrict__ G1, const float* __restrict__ G2,
                                                const float* __restrict__ gmax,
                                                float* __restrict__ E1, float* __restrict__ E2,
                                                float* __restrict__ rs)
{
    const float inv_sqrt_n = 4.4721359549995794e-3f;
    int i = blockIdx.x, z = blockIdx.y, j = threadIdx.x;
    const float* G = z ? G2 : G1;
    float* E = z ? E2 : E1;
    float e = expf((G[i * 256 + j] - gmax[z]) * inv_sqrt_n);
    E[i * 256 + j] = e;
    float v = e;
    for (int m = 1; m < 64; m <<= 1) v += __shfl_xor(v, m);
    __shared__ float wm[4];
    if ((j & 63) == 0) wm[j >> 6] = v;
    __syncthreads();
    if (j == 0) rs[z * 256 + i] = wm[0] + wm[1] + wm[2] + wm[3];
}

__global__ __launch_bounds__(256) void k_colsum(const float* __restrict__ E1, const float* __restrict__ E2,
                                                float* __restrict__ cs)
{
    int b = blockIdx.x, z = blockIdx.y, j = threadIdx.x;
    const float* E = z ? E2 : E1;
    float a = 0.f;
    for (int i = b * 32; i < b * 32 + 32; ++i) a += E[i * 256 + j];
    atomicAdd(&cs[z * 256 + j], a);
}

__global__ __launch_bounds__(256) void k_smacc(const float* __restrict__ E1, const float* __restrict__ E2,
                                               const float* __restrict__ rs, const float* __restrict__ cs,
                                               float* __restrict__ SMh)
{
    int i = blockIdx.x, j = threadIdx.x;
    float v1 = E1[i * 256 + j] * rsqrtf(rs[i] + 1e-10f) * rsqrtf(cs[j] + 1e-10f);
    float v2 = E2[i * 256 + j] * rsqrtf(rs[256 + i] + 1e-10f) * rsqrtf(cs[256 + j] + 1e-10f);
    SMh[i * 256 + j] = 0.25f * (v1 + v2);
}

__global__ void k_sinit(const float* __restrict__ SMh, float* __restrict__ S)
{
    int i = blockIdx.x, j = threadIdx.x;
    S[i * 256 + j] = SMh[i * 256 + j] + (i == j ? 1.0f : 0.0f);
}

__global__ __launch_bounds__(256) void k_sgemm(const float* __restrict__ P, const float* __restrict__ SMh,
                                               float* __restrict__ Pn, float* __restrict__ S)
{
    __shared__ float pr[256];
    int i = blockIdx.x, j = threadIdx.x;
    pr[j] = P[i * 256 + j];
    __syncthreads();
    float a = 0.f;
    for (int k = 0; k < 256; ++k) a += pr[k] * SMh[k * 256 + j];
    Pn[i * 256 + j] = a;
    S[i * 256 + j] += a;
}

// ---------------- ZM: in-place average of the two bf16 copies ----------------
__global__ void k_zm(unsigned short* __restrict__ A, unsigned short* __restrict__ B)
{
    size_t i = ((size_t)blockIdx.x * 256 + threadIdx.x) * 8;
    u16x8 a = *(const u16x8*)(A + i), b = *(const u16x8*)(B + i);
    u16x8 c;
    for (int q = 0; q < 8; ++q) c[q] = f2bf(0.5f * (bf2f(a[q]) + bf2f(b[q])));
    *(u16x8*)(A + i) = c;
    *(u16x8*)(B + i) = c;
}

// ---------------- CSR build: hist + 3-phase parallel scan + scatter ----------------
__global__ void k_hist(const int* __restrict__ src, int* __restrict__ counts)
{
    int e = blockIdx.x * 256 + threadIdx.x;
    atomicAdd(&counts[src[e]], 1);
}

__global__ __launch_bounds__(256) void k_bsum(const int* __restrict__ counts, int* __restrict__ bsum)
{
    int i = blockIdx.x * 256 + threadIdx.x;
    int v = (i < N_NODES) ? counts[i] : 0;
    for (int m = 1; m < 64; m <<= 1) v += __shfl_xor(v, m);
    __shared__ int wm[4];
    if ((threadIdx.x & 63) == 0) wm[threadIdx.x >> 6] = v;
    __syncthreads();
    if (threadIdx.x == 0) bsum[blockIdx.x] = wm[0] + wm[1] + wm[2] + wm[3];
}

__global__ __launch_bounds__(256) void k_bscan(const int* __restrict__ bsum, int* __restrict__ boff,
                                               int* __restrict__ rowptr)
{
    __shared__ int tmp[256];
    int t = threadIdx.x;
    int v = (t < NBLK_SCAN) ? bsum[t] : 0;
    tmp[t] = v;
    __syncthreads();
    for (int off = 1; off < 256; off <<= 1) {
        int add = (t >= off) ? tmp[t - off] : 0;
        __syncthreads();
        tmp[t] += add;
        __syncthreads();
    }
    if (t < NBLK_SCAN) boff[t] = tmp[t] - v;
    if (t == NBLK_SCAN - 1) rowptr[N_NODES] = tmp[t];
}

__global__ __launch_bounds__(256) void k_rowptr(const int* __restrict__ counts, const int* __restrict__ boff,
                                                int* __restrict__ rowptr, int* __restrict__ cursor)
{
    __shared__ int tmp[256];
    int b = blockIdx.x, t = threadIdx.x;
    int i = b * 256 + t;
    int v = (i < N_NODES) ? counts[i] : 0;
    tmp[t] = v;
    __syncthreads();
    for (int off = 1; off < 256; off <<= 1) {
        int add = (t >= off) ? tmp[t - off] : 0;
        __syncthreads();
        tmp[t] += add;
        __syncthreads();
    }
    int excl = tmp[t] - v + boff[b];
    if (i < N_NODES) { rowptr[i] = excl; cursor[i] = excl; }
}

__global__ void k_scatter(const int* __restrict__ src, const int* __restrict__ dst,
                          const float* __restrict__ val, int* __restrict__ cursor,
                          int* __restrict__ sdst, float* __restrict__ sval)
{
    int e = blockIdx.x * 256 + threadIdx.x;
    int s = src[e];
    int pos = atomicAdd(&cursor[s], 1);
    sdst[pos] = dst[e];
    sval[pos] = val[e];
}

// ---------------- SpMM layer: nxt = 0.5 * A @ cur ; PA += nxt (bf16, unroll-8 ILP) ----------------
__global__ __launch_bounds__(256) void k_spmm(const int* __restrict__ rowptr, const int* __restrict__ sdst,
                                              const float* __restrict__ sval,
                                              const unsigned short* __restrict__ cur,
                                              unsigned short* __restrict__ nxt, unsigned short* __restrict__ PA)
{
    __shared__ int ed[256];
    __shared__ float ev[256];
    int i = blockIdx.x, j = threadIdx.x;
    int lo = rowptr[i], hi = rowptr[i + 1];
    float a0 = 0.f, a1 = 0.f, a2 = 0.f, a3 = 0.f;
    float a4 = 0.f, a5 = 0.f, a6 = 0.f, a7 = 0.f;
    for (int base = lo; base < hi; base += 256) {
        int cnt = min(hi - base, 256);
        __syncthreads();
        if (j < cnt) { ed[j] = sdst[base + j]; ev[j] = sval[base + j]; }
        __syncthreads();
        int q = 0;
        for (; q + 8 <= cnt; q += 8) {
            a0 += ev[q + 0] * bf2f(cur[(size_t)ed[q + 0] * 256 + j]);
            a1 += ev[q + 1] * bf2f(cur[(size_t)ed[q + 1] * 256 + j]);
            a2 += ev[q + 2] * bf2f(cur[(size_t)ed[q + 2] * 256 + j]);
            a3 += ev[q + 3] * bf2f(cur[(size_t)ed[q + 3] * 256 + j]);
            a4 += ev[q + 4] * bf2f(cur[(size_t)ed[q + 4] * 256 + j]);
            a5 += ev[q + 5] * bf2f(cur[(size_t)ed[q + 5] * 256 + j]);
            a6 += ev[q + 6] * bf2f(cur[(size_t)ed[q + 6] * 256 + j]);
            a7 += ev[q + 7] * bf2f(cur[(size_t)ed[q + 7] * 256 + j]);
        }
        for (; q < cnt; ++q)
            a0 += ev[q] * bf2f(cur[(size_t)ed[q] * 256 + j]);
    }
    float v = 0.5f * (((a0 + a1) + (a2 + a3)) + ((a4 + a5) + (a6 + a7)));
    size_t idx = (size_t)i * 256 + j;
    nxt[idx] = f2bf(v);
    PA[idx] = f2bf(bf2f(PA[idx]) + v);
}

// ---------------- diagnostic stamps ----------------
__global__ void k_stamp(float* __restrict__ out, float c0, float c1, float c2)
{
    if (c0 != 0.f) out[0] = c0;
    if (c1 != 0.f) out[1] = c1;
    if (c2 != 0.f) out[2] = c2;
}

extern "C" void kernel_launch(void* const* d_in, const int* in_sizes, int n_in,
                              void* d_out, int out_size, void* d_ws, size_t ws_size,
                              hipStream_t stream)
{
    const float* X1   = (const float*)d_in[0];
    const float* X2   = (const float*)d_in[1];
    const int*   esrc = (const int*)d_in[2];
    const int*   edst = (const int*)d_in[3];
    const float* eval = (const float*)d_in[4];
    const float* W1   = (const float*)d_in[5];
    const float* b1   = (const float*)d_in[6];
    const float* W2   = (const float*)d_in[7];
    const float* b2   = (const float*)d_in[8];

    float* out_zm1 = (float*)d_out;
    float* out_zm2 = out_zm1 + (size_t)N_NODES * 256;
    float* out_hm  = out_zm2 + (size_t)N_NODES * 256;

    // ---- workspace carve (~61.2 MB) ----
    char* w = (char*)d_ws;
    unsigned short* PAb   = (unsigned short*)w; w += 25600000;   // Zb2 -> ZM -> part_alpha
    unsigned short* curA  = (unsigned short*)w; w += 25600000;   // Zb1 -> ZM ping
    int* sdst             = (int*)w;            w += 3200000;
    float* sval           = (float*)w;          w += 3200000;
    int* counts           = (int*)w;            w += 200192;
    int* rowptr           = (int*)w;            w += 200192;
    int* cursor           = (int*)w;            w += 200192;
    float* G1             = (float*)w;          w += 262144;
    float* G2             = (float*)w;          w += 262144;
    float* E1             = (float*)w;          w += 262144;
    float* E2             = (float*)w;          w += 262144;
    float* SMh            = (float*)w;          w += 262144;
    float* S              = (float*)w;          w += 262144;
    float* P2             = (float*)w;          w += 262144;
    float* P3             = (float*)w;          w += 262144;
    float* rs             = (float*)w;          w += 2048;
    float* cs             = (float*)w;          w += 2048;
    float* gmax           = (float*)w;          w += 256;
    int* bsum             = (int*)w;            w += 1024;
    int* boff             = (int*)w;            w += 1024;
    unsigned short* Wt1   = (unsigned short*)w; w += 393216;
    unsigned short* Wt2   = (unsigned short*)w; w += 262144;
    unsigned short* St    = (unsigned short*)w; w += 131072;
    size_t ws_need = (size_t)(w - (char*)d_ws);

    unsigned short* curB  = (unsigned short*)out_hm;   // dead until k_hm

    bool sizes_ok = (n_in == 9)
        && in_sizes[0] == 38400000 && in_sizes[1] == 25600000
        && in_sizes[2] == 800000 && in_sizes[3] == 800000 && in_sizes[4] == 800000
        && in_sizes[5] == 196608 && in_sizes[6] == 256
        && in_sizes[7] == 131072 && in_sizes[8] == 256;
    float c0 = (n_in != 9) ? 1000.f : 0.f;
    float c1 = (!sizes_ok && n_in == 9) ? 2000.f : 0.f;
    float c2 = (ws_size < ws_need) ? (4000.f + (float)(ws_size / 1000000ull)) : 0.f;

    // 0) weights -> bf16 transposed
    k_wt<<<768, 256, 0, stream>>>(W1, Wt1, 768);
    k_wt<<<512, 256, 0, stream>>>(W2, Wt2, 512);

    // 1) ZM1/ZM2 via MFMA 128-row tiles (2x4 wave grid), dual fp32+bf16 store
    k_gemm_mfma<<<(N_NODES + 127) / 128, 512, 0, stream>>>(X1, Wt1, b1, out_zm1, curA, N_NODES, 768);
    k_gemm_mfma<<<(N_NODES + 127) / 128, 512, 0, stream>>>(X2, Wt2, b2, out_zm2, PAb, N_NODES, 512);

    // 2) Grams + fused/batched softmax chain
    hipMemsetAsync(G1, 0, 262144, stream);
    hipMemsetAsync(G2, 0, 262144, stream);
    hipMemsetAsync(cs, 0, 2048, stream);
    k_gram_mfma<<<dim3(2, 49, 2), 512, 0, stream>>>(curA, PAb, G1, G2, N_NODES);
    k_max2<<<2, 256, 0, stream>>>(G1, G2, gmax);
    k_exprow<<<dim3(256, 2), 256, 0, stream>>>(G1, G2, gmax, E1, E2, rs);
    k_colsum<<<dim3(8, 2), 256, 0, stream>>>(E1, E2, cs);
    k_smacc<<<256, 256, 0, stream>>>(E1, E2, rs, cs, SMh);

    // 3) ZM: in-place average of Zb1 (curA) and Zb2 (PAb)
    k_zm<<<6250, 256, 0, stream>>>(curA, PAb);

    // 4) CSR by src (parallel 3-phase scan)
    hipMemsetAsync(counts, 0, 200192, stream);
    k_hist<<<NE / 256, 256, 0, stream>>>(esrc, counts);
    k_bsum<<<NBLK_SCAN, 256, 0, stream>>>(counts, bsum);
    k_bscan<<<1, 256, 0, stream>>>(bsum, boff, rowptr);
    k_rowptr<<<NBLK_SCAN, 256, 0, stream>>>(counts, boff, rowptr, cursor);
    k_scatter<<<NE / 256, 256, 0, stream>>>(esrc, edst, eval, cursor, sdst, sval);

    // 5) 4 propagation layers (curB parked in out_hm region)
    k_spmm<<<N_NODES, 256, 0, stream>>>(rowptr, sdst, sval, curA, curB, PAb);
    k_spmm<<<N_NODES, 256, 0, stream>>>(rowptr, sdst, sval, curB, curA, PAb);
    k_spmm<<<N_NODES, 256, 0, stream>>>(rowptr, sdst, sval, curA, curB, PAb);
    k_spmm<<<N_NODES, 256, 0, stream>>>(rowptr, sdst, sval, curB, curA, PAb);

    // 6) S = I + B + B^2 + B^3, then St = bf16(S^T)
    k_sinit<<<256, 256, 0, stream>>>(SMh, S);
    k_sgemm<<<256, 256, 0, stream>>>(SMh, SMh, P2, S);
    k_sgemm<<<256, 256, 0, stream>>>(P2, SMh, P3, S);
    k_st<<<256, 256, 0, stream>>>(S, St);

    // 7) HM = l2norm(PA @ S) via MFMA 128-row tiles (2x4 wave grid)
    k_hm_mfma<<<(N_NODES + 127) / 128, 512, 0, stream>>>(PAb, St, out_hm, N_NODES);

    // 8) diagnostic stamps
    k_stamp<<<1, 1, 0, stream>>>(out_zm1, c0, c1, c2);
}

// Round 14
// 782.211 us; speedup vs baseline: 2.4250x; 1.0082x over previous
//
#include <hip/hip_runtime.h>
#include <hip/hip_bf16.h>

#define N_NODES 50000
#define NE      800000
#define NBLK_SCAN 196   // ceil(50000/256)

typedef __attribute__((ext_vector_type(4))) float f32x4;
typedef __attribute__((ext_vector_type(8))) short s16x8;
typedef __attribute__((ext_vector_type(8))) unsigned short u16x8;

__device__ __forceinline__ float bf2f(unsigned short u) {
    union { unsigned int i; float f; } v; v.i = ((unsigned int)u) << 16; return v.f;
}
__device__ __forceinline__ unsigned short f2bf(float f) {
    union { unsigned int i; float f; } v; v.f = f;
    unsigned int x = v.i;
    return (unsigned short)((x + 0x7fffu + ((x >> 16) & 1u)) >> 16);  // RNE
}

// ---------------- weights: W fp32 (K,256) C-order -> Wt bf16 [256][K] ----------------
__global__ void k_wt(const float* __restrict__ W, unsigned short* __restrict__ Wt, int K)
{
    int idx = blockIdx.x * 256 + threadIdx.x;          // = j*K + k
    int j = idx / K, k = idx - j * K;
    Wt[idx] = f2bf(W[(size_t)k * 256 + j]);
}

// ---------------- S fp32 [256][256] -> St bf16 transposed ----------------
__global__ void k_st(const float* __restrict__ S, unsigned short* __restrict__ St)
{
    int k = blockIdx.x, j = threadIdx.x;
    St[j * 256 + k] = f2bf(S[k * 256 + j]);
}

// ---------------- GEMM + bias + row l2norm, bf16 MFMA; 128x256 tile, 2x4 waves,
//                  register-prefetch pipelined K-loop ----------------
__global__ __launch_bounds__(512) void k_gemm_mfma(
    const float* __restrict__ X, const unsigned short* __restrict__ Wt,
    const float* __restrict__ bias, float* __restrict__ out,
    unsigned short* __restrict__ Zb, int M, int K)
{
    __shared__ unsigned short Alds[128][72];
    __shared__ unsigned short Blds[256][72];
    __shared__ float part[4][136];
    const int tid = threadIdx.x;
    const int m0 = blockIdx.x * 128;
    const int wave = tid >> 6, lane = tid & 63;
    const int wr = wave >> 2, wc = wave & 3;
    const int l15 = lane & 15, lg = lane >> 4;

    // per-thread staging coordinates (fixed across K-steps)
    int ar[4], ac4[4], bj[4], bk8[4];
    const float* aptr[4];
    const unsigned short* bptr[4];
    for (int p = 0; p < 4; ++p) {
        int idx = tid + p * 512;
        ar[p] = idx >> 4; ac4[p] = idx & 15;
        bj[p] = idx >> 3; bk8[p] = idx & 7;
        int row = m0 + ar[p];
        aptr[p] = (row < M) ? (X + (size_t)row * K + ac4[p] * 4) : nullptr;
        bptr[p] = Wt + (size_t)bj[p] * K + bk8[p] * 8;
    }

    f32x4 acc[4][4];
    for (int a = 0; a < 4; ++a) for (int b = 0; b < 4; ++b) acc[a][b] = (f32x4)0.0f;

    float4 avr[4];
    u16x8 bvr[4];
    // prefetch tile 0
    for (int p = 0; p < 4; ++p) {
        avr[p] = aptr[p] ? *(const float4*)(aptr[p]) : make_float4(0.f, 0.f, 0.f, 0.f);
        bvr[p] = *(const u16x8*)(bptr[p]);
    }

    const int NT = K >> 6;
    for (int t = 0; t < NT; ++t) {
        __syncthreads();                       // LDS free (prev MFMA done)
        for (int p = 0; p < 4; ++p) {
            ushort4 pk;
            pk.x = f2bf(avr[p].x); pk.y = f2bf(avr[p].y);
            pk.z = f2bf(avr[p].z); pk.w = f2bf(avr[p].w);
            *(ushort4*)&Alds[ar[p]][ac4[p] * 4] = pk;
            *(u16x8*)&Blds[bj[p]][bk8[p] * 8] = bvr[p];
        }
        if (t + 1 < NT) {                      // issue next-tile loads: latency hides under barrier+MFMA
            int k0 = (t + 1) * 64;
            for (int p = 0; p < 4; ++p) {
                avr[p] = aptr[p] ? *(const float4*)(aptr[p] + k0) : make_float4(0.f, 0.f, 0.f, 0.f);
                bvr[p] = *(const u16x8*)(bptr[p] + k0);
            }
        }
        __syncthreads();                       // LDS visible
        for (int kk = 0; kk < 2; ++kk) {
            s16x8 af[4], bfr[4];
            for (int mt = 0; mt < 4; ++mt)
                af[mt] = *(const s16x8*)&Alds[wr * 64 + mt * 16 + l15][kk * 32 + lg * 8];
            for (int nt = 0; nt < 4; ++nt)
                bfr[nt] = *(const s16x8*)&Blds[wc * 64 + nt * 16 + l15][kk * 32 + lg * 8];
            for (int mt = 0; mt < 4; ++mt)
                for (int nt = 0; nt < 4; ++nt)
                    acc[mt][nt] = __builtin_amdgcn_mfma_f32_16x16x32_bf16(af[mt], bfr[nt], acc[mt][nt], 0, 0, 0);
        }
    }

    // bias + per-wave (64-col) sumsq partials, reduced over l15
    for (int mt = 0; mt < 4; ++mt) {
        for (int nt = 0; nt < 4; ++nt) {
            float bb = bias[wc * 64 + nt * 16 + l15];
            for (int r = 0; r < 4; ++r) acc[mt][nt][r] += bb;
        }
        for (int r = 0; r < 4; ++r) {
            float p = 0.f;
            for (int nt = 0; nt < 4; ++nt) p += acc[mt][nt][r] * acc[mt][nt][r];
            p += __shfl_xor(p, 1); p += __shfl_xor(p, 2);
            p += __shfl_xor(p, 4); p += __shfl_xor(p, 8);
            if (l15 == 0) part[wc][wr * 64 + mt * 16 + lg * 4 + r] = p;
        }
    }
    __syncthreads();
    for (int mt = 0; mt < 4; ++mt) {
        for (int r = 0; r < 4; ++r) {
            int rl = wr * 64 + mt * 16 + lg * 4 + r;
            float s = part[0][rl] + part[1][rl] + part[2][rl] + part[3][rl];
            float inv = 1.0f / fmaxf(sqrtf(s), 1e-12f);
            int row = m0 + rl;
            if (row < M) {
                for (int nt = 0; nt < 4; ++nt) {
                    float v = acc[mt][nt][r] * inv;
                    size_t o = (size_t)row * 256 + wc * 64 + nt * 16 + l15;
                    out[o] = v;
                    Zb[o] = f2bf(v);
                }
            }
        }
    }
}

// ---------------- Gram via MFMA: bf16 source, 128-row slabs, 8-wave blocks ----------------
__global__ __launch_bounds__(512) void k_gram_mfma(
    const unsigned short* __restrict__ Zb1, const unsigned short* __restrict__ Zb2,
    float* __restrict__ G1, float* __restrict__ G2, int M)
{
    __shared__ unsigned short Zt[256][72];
    const unsigned short* Z = blockIdx.z ? Zb2 : Zb1;
    float* G = blockIdx.z ? G2 : G1;
    const int tid = threadIdx.x;
    const int ib = blockIdx.x;
    const int wave = tid >> 6, lane = tid & 63;
    const int l15 = lane & 15, lg = lane >> 4;
    const int TC = (M + 63) >> 6;                 // 782
    const int c0 = blockIdx.y * 16;
    const int c1 = min(c0 + 16, TC);

    const int ja = ib * 128 + wave * 16 + l15;
    const int sa = ((ja >> 2) & 7) << 3;

    f32x4 acc[16];
    for (int i = 0; i < 16; ++i) acc[i] = (f32x4)0.0f;

    for (int ch = c0; ch < c1; ++ch) {
        int base = ch * 64;
        __syncthreads();
        for (int p = 0; p < 4; ++p) {
            int idx = tid + p * 512;              // 2048 u16x8 = 64 m x 32 c8
            int m = idx >> 5, c8 = idx & 31;
            int row = base + m;
            u16x8 v = (u16x8)0;
            if (row < M) v = *(const u16x8*)(Z + (size_t)row * 256 + c8 * 8);
            for (int q = 0; q < 8; ++q) {
                int f = c8 * 8 + q;
                int cs = m ^ (((f >> 2) & 7) << 3);
                Zt[f][cs] = v[q];
            }
        }
        __syncthreads();
        for (int kk = 0; kk < 2; ++kk) {
            s16x8 a = *(const s16x8*)&Zt[ja][(kk * 32 + lg * 8) ^ sa];
            for (int nt = 0; nt < 16; ++nt) {
                int jb = nt * 16 + l15;
                int sb = ((jb >> 2) & 7) << 3;
                s16x8 b = *(const s16x8*)&Zt[jb][(kk * 32 + lg * 8) ^ sb];
                acc[nt] = __builtin_amdgcn_mfma_f32_16x16x32_bf16(a, b, acc[nt], 0, 0, 0);
            }
        }
    }
    for (int nt = 0; nt < 16; ++nt)
        for (int r = 0; r < 4; ++r)
            atomicAdd(&G[(ib * 128 + wave * 16 + lg * 4 + r) * 256 + nt * 16 + l15], acc[nt][r]);
}

// ---------------- HM = l2norm(PA @ S) via MFMA; 128x256 tile, 2x4 waves, prefetch ----------------
__global__ __launch_bounds__(512) void k_hm_mfma(const unsigned short* __restrict__ PA,
                                                 const unsigned short* __restrict__ St,
                                                 float* __restrict__ out, int M)
{
    __shared__ unsigned short Alds[128][72];
    __shared__ unsigned short Blds[256][72];
    __shared__ float part[4][136];
    const int tid = threadIdx.x;
    const int m0 = blockIdx.x * 128;
    const int wave = tid >> 6, lane = tid & 63;
    const int wr = wave >> 2, wc = wave & 3;
    const int l15 = lane & 15, lg = lane >> 4;

    int ar2[2], ak8[2], bj[4], bk8[4];
    const unsigned short* aptr[2];
    const unsigned short* bptr[4];
    for (int p = 0; p < 2; ++p) {
        int idx = tid + p * 512;
        ar2[p] = idx >> 3; ak8[p] = idx & 7;
        int row = m0 + ar2[p];
        aptr[p] = (row < M) ? (PA + (size_t)row * 256 + ak8[p] * 8) : nullptr;
    }
    for (int p = 0; p < 4; ++p) {
        int idx = tid + p * 512;
        bj[p] = idx >> 3; bk8[p] = idx & 7;
        bptr[p] = St + (size_t)bj[p] * 256 + bk8[p] * 8;
    }

    f32x4 acc[4][4];
    for (int a = 0; a < 4; ++a) for (int b = 0; b < 4; ++b) acc[a][b] = (f32x4)0.0f;

    u16x8 avr[2], bvr[4];
    for (int p = 0; p < 2; ++p) avr[p] = aptr[p] ? *(const u16x8*)(aptr[p]) : (u16x8)0;
    for (int p = 0; p < 4; ++p) bvr[p] = *(const u16x8*)(bptr[p]);

    for (int t = 0; t < 4; ++t) {
        __syncthreads();
        for (int p = 0; p < 2; ++p) *(u16x8*)&Alds[ar2[p]][ak8[p] * 8] = avr[p];
        for (int p = 0; p < 4; ++p) *(u16x8*)&Blds[bj[p]][bk8[p] * 8] = bvr[p];
        if (t < 3) {
            int k0 = (t + 1) * 64;
            for (int p = 0; p < 2; ++p) avr[p] = aptr[p] ? *(const u16x8*)(aptr[p] + k0) : (u16x8)0;
            for (int p = 0; p < 4; ++p) bvr[p] = *(const u16x8*)(bptr[p] + k0);
        }
        __syncthreads();
        for (int kk = 0; kk < 2; ++kk) {
            s16x8 af[4], bfr[4];
            for (int mt = 0; mt < 4; ++mt)
                af[mt] = *(const s16x8*)&Alds[wr * 64 + mt * 16 + l15][kk * 32 + lg * 8];
            for (int nt = 0; nt < 4; ++nt)
                bfr[nt] = *(const s16x8*)&Blds[wc * 64 + nt * 16 + l15][kk * 32 + lg * 8];
            for (int mt = 0; mt < 4; ++mt)
                for (int nt = 0; nt < 4; ++nt)
                    acc[mt][nt] = __builtin_amdgcn_mfma_f32_16x16x32_bf16(af[mt], bfr[nt], acc[mt][nt], 0, 0, 0);
        }
    }

    for (int mt = 0; mt < 4; ++mt) {
        for (int r = 0; r < 4; ++r) {
            float p = 0.f;
            for (int nt = 0; nt < 4; ++nt) p += acc[mt][nt][r] * acc[mt][nt][r];
            p += __shfl_xor(p, 1); p += __shfl_xor(p, 2);
            p += __shfl_xor(p, 4); p += __shfl_xor(p, 8);
            if (l15 == 0) part[wc][wr * 64 + mt * 16 + lg * 4 + r] = p;
        }
    }
    __syncthreads();
    for (int mt = 0; mt < 4; ++mt) {
        for (int r = 0; r < 4; ++r) {
            int rl = wr * 64 + mt * 16 + lg * 4 + r;
            float s = part[0][rl] + part[1][rl] + part[2][rl] + part[3][rl];
            float inv = 1.0f / fmaxf(sqrtf(s), 1e-12f);
            int row = m0 + rl;
            if (row < M) {
                for (int nt = 0; nt < 4; ++nt)
                    out[(size_t)row * 256 + wc * 64 + nt * 16 + l15] = acc[mt][nt][r] * inv;
            }
        }
    }
}

// ---------------- fused softmax helpers (batched over both matrices) ----------------
__global__ __launch_bounds__(256) void k_max2(const float* __restrict__ G1, const float* __restrict__ G2,
                                              float* __restrict__ gmax)
{
    const float* G = blockIdx.x ? G2 : G1;
    float m = -1e30f;
    for (int i = threadIdx.x; i < 65536; i += 256) m = fmaxf(m, G[i]);
    for (int s = 1; s < 64; s <<= 1) m = fmaxf(m, __shfl_xor(m, s));
    __shared__ float wm[4];
    if ((threadIdx.x & 63) == 0) wm[threadIdx.x >> 6] = m;
    __syncthreads();
    if (threadIdx.x == 0) gmax[blockIdx.x] = fmaxf(fmaxf(wm[0], wm[1]), fmaxf(wm[2], wm[3]));
}

__global__ __launch_bounds__(256) void k_exprow(const float* __restrict__ G1, const float* __restrict__ G2,
                                                const float* __restrict__ gmax,
                                                float* __restrict__ E1, float* __restrict__ E2,
                                                float* __restrict__ rs)
{
    const float inv_sqrt_n = 4.4721359549995794e-3f;
    int i = blockIdx.x, z = blockIdx.y, j = threadIdx.x;
    const float* G = z ? G2 : G1;
    float* E = z ? E2 : E1;
    float e = expf((G[i * 256 + j] - gmax[z]) * inv_sqrt_n);
    E[i * 256 + j] = e;
    float v = e;
    for (int m = 1; m < 64; m <<= 1) v += __shfl_xor(v, m);
    __shared__ float wm[4];
    if ((j & 63) == 0) wm[j >> 6] = v;
    __syncthreads();
    if (j == 0) rs[z * 256 + i] = wm[0] + wm[1] + wm[2] + wm[3];
}

__global__ __launch_bounds__(256) void k_colsum(const float* __restrict__ E1, const float* __restrict__ E2,
                                                float* __restrict__ cs)
{
    int b = blockIdx.x, z = blockIdx.y, j = threadIdx.x;
    const float* E = z ? E2 : E1;
    float a = 0.f;
    for (int i = b * 32; i < b * 32 + 32; ++i) a += E[i * 256 + j];
    atomicAdd(&cs[z * 256 + j], a);
}

__global__ __launch_bounds__(256) void k_smacc(const float* __restrict__ E1, const float* __restrict__ E2,
                                               const float* __restrict__ rs, const float* __restrict__ cs,
                                               float* __restrict__ SMh)
{
    int i = blockIdx.x, j = threadIdx.x;
    float v1 = E1[i * 256 + j] * rsqrtf(rs[i] + 1e-10f) * rsqrtf(cs[j] + 1e-10f);
    float v2 = E2[i * 256 + j] * rsqrtf(rs[256 + i] + 1e-10f) * rsqrtf(cs[256 + j] + 1e-10f);
    SMh[i * 256 + j] = 0.25f * (v1 + v2);
}

__global__ void k_sinit(const float* __restrict__ SMh, float* __restrict__ S)
{
    int i = blockIdx.x, j = threadIdx.x;
    S[i * 256 + j] = SMh[i * 256 + j] + (i == j ? 1.0f : 0.0f);
}

__global__ __launch_bounds__(256) void k_sgemm(const float* __restrict__ P, const float* __restrict__ SMh,
                                               float* __restrict__ Pn, float* __restrict__ S)
{
    __shared__ float pr[256];
    int i = blockIdx.x, j = threadIdx.x;
    pr[j] = P[i * 256 + j];
    __syncthreads();
    float a = 0.f;
    for (int k = 0; k < 256; ++k) a += pr[k] * SMh[k * 256 + j];
    Pn[i * 256 + j] = a;
    S[i * 256 + j] += a;
}

// ---------------- ZM: in-place average of the two bf16 copies ----------------
__global__ void k_zm(unsigned short* __restrict__ A, unsigned short* __restrict__ B)
{
    size_t i = ((size_t)blockIdx.x * 256 + threadIdx.x) * 8;
    u16x8 a = *(const u16x8*)(A + i), b = *(const u16x8*)(B + i);
    u16x8 c;
    for (int q = 0; q < 8; ++q) c[q] = f2bf(0.5f * (bf2f(a[q]) + bf2f(b[q])));
    *(u16x8*)(A + i) = c;
    *(u16x8*)(B + i) = c;
}

// ---------------- CSR build: hist + 3-phase parallel scan + scatter ----------------
__global__ void k_hist(const int* __restrict__ src, int* __restrict__ counts)
{
    int e = blockIdx.x * 256 + threadIdx.x;
    atomicAdd(&counts[src[e]], 1);
}

__global__ __launch_bounds__(256) void k_bsum(const int* __restrict__ counts, int* __restrict__ bsum)
{
    int i = blockIdx.x * 256 + threadIdx.x;
    int v = (i < N_NODES) ? counts[i] : 0;
    for (int m = 1; m < 64; m <<= 1) v += __shfl_xor(v, m);
    __shared__ int wm[4];
    if ((threadIdx.x & 63) == 0) wm[threadIdx.x >> 6] = v;
    __syncthreads();
    if (threadIdx.x == 0) bsum[blockIdx.x] = wm[0] + wm[1] + wm[2] + wm[3];
}

__global__ __launch_bounds__(256) void k_bscan(const int* __restrict__ bsum, int* __restrict__ boff,
                                               int* __restrict__ rowptr)
{
    __shared__ int tmp[256];
    int t = threadIdx.x;
    int v = (t < NBLK_SCAN) ? bsum[t] : 0;
    tmp[t] = v;
    __syncthreads();
    for (int off = 1; off < 256; off <<= 1) {
        int add = (t >= off) ? tmp[t - off] : 0;
        __syncthreads();
        tmp[t] += add;
        __syncthreads();
    }
    if (t < NBLK_SCAN) boff[t] = tmp[t] - v;
    if (t == NBLK_SCAN - 1) rowptr[N_NODES] = tmp[t];
}

__global__ __launch_bounds__(256) void k_rowptr(const int* __restrict__ counts, const int* __restrict__ boff,
                                                int* __restrict__ rowptr, int* __restrict__ cursor)
{
    __shared__ int tmp[256];
    int b = blockIdx.x, t = threadIdx.x;
    int i = b * 256 + t;
    int v = (i < N_NODES) ? counts[i] : 0;
    tmp[t] = v;
    __syncthreads();
    for (int off = 1; off < 256; off <<= 1) {
        int add = (t >= off) ? tmp[t - off] : 0;
        __syncthreads();
        tmp[t] += add;
        __syncthreads();
    }
    int excl = tmp[t] - v + boff[b];
    if (i < N_NODES) { rowptr[i] = excl; cursor[i] = excl; }
}

__global__ void k_scatter(const int* __restrict__ src, const int* __restrict__ dst,
                          const float* __restrict__ val, int* __restrict__ cursor,
                          int* __restrict__ sdst, float* __restrict__ sval)
{
    int e = blockIdx.x * 256 + threadIdx.x;
    int s = src[e];
    int pos = atomicAdd(&cursor[s], 1);
    sdst[pos] = dst[e];
    sval[pos] = val[e];
}

// ---------------- SpMM layer: nxt = 0.5 * A @ cur ; PA += nxt (bf16, unroll-8 ILP) ----------------
__global__ __launch_bounds__(256) void k_spmm(const int* __restrict__ rowptr, const int* __restrict__ sdst,
                                              const float* __restrict__ sval,
                                              const unsigned short* __restrict__ cur,
                                              unsigned short* __restrict__ nxt, unsigned short* __restrict__ PA)
{
    __shared__ int ed[256];
    __shared__ float ev[256];
    int i = blockIdx.x, j = threadIdx.x;
    int lo = rowptr[i], hi = rowptr[i + 1];
    float a0 = 0.f, a1 = 0.f, a2 = 0.f, a3 = 0.f;
    float a4 = 0.f, a5 = 0.f, a6 = 0.f, a7 = 0.f;
    for (int base = lo; base < hi; base += 256) {
        int cnt = min(hi - base, 256);
        __syncthreads();
        if (j < cnt) { ed[j] = sdst[base + j]; ev[j] = sval[base + j]; }
        __syncthreads();
        int q = 0;
        for (; q + 8 <= cnt; q += 8) {
            a0 += ev[q + 0] * bf2f(cur[(size_t)ed[q + 0] * 256 + j]);
            a1 += ev[q + 1] * bf2f(cur[(size_t)ed[q + 1] * 256 + j]);
            a2 += ev[q + 2] * bf2f(cur[(size_t)ed[q + 2] * 256 + j]);
            a3 += ev[q + 3] * bf2f(cur[(size_t)ed[q + 3] * 256 + j]);
            a4 += ev[q + 4] * bf2f(cur[(size_t)ed[q + 4] * 256 + j]);
            a5 += ev[q + 5] * bf2f(cur[(size_t)ed[q + 5] * 256 + j]);
            a6 += ev[q + 6] * bf2f(cur[(size_t)ed[q + 6] * 256 + j]);
            a7 += ev[q + 7] * bf2f(cur[(size_t)ed[q + 7] * 256 + j]);
        }
        for (; q < cnt; ++q)
            a0 += ev[q] * bf2f(cur[(size_t)ed[q] * 256 + j]);
    }
    float v = 0.5f * (((a0 + a1) + (a2 + a3)) + ((a4 + a5) + (a6 + a7)));
    size_t idx = (size_t)i * 256 + j;
    nxt[idx] = f2bf(v);
    PA[idx] = f2bf(bf2f(PA[idx]) + v);
}

// ---------------- diagnostic stamps ----------------
__global__ void k_stamp(float* __restrict__ out, float c0, float c1, float c2)
{
    if (c0 != 0.f) out[0] = c0;
    if (c1 != 0.f) out[1] = c1;
    if (c2 != 0.f) out[2] = c2;
}

extern "C" void kernel_launch(void* const* d_in, const int* in_sizes, int n_in,
                              void* d_out, int out_size, void* d_ws, size_t ws_size,
                              hipStream_t stream)
{
    const float* X1   = (const float*)d_in[0];
    const float* X2   = (const float*)d_in[1];
    const int*   esrc = (const int*)d_in[2];
    const int*   edst = (const int*)d_in[3];
    const float* eval = (const float*)d_in[4];
    const float* W1   = (const float*)d_in[5];
    const float* b1   = (const float*)d_in[6];
    const float* W2   = (const float*)d_in[7];
    const float* b2   = (const float*)d_in[8];

    float* out_zm1 = (float*)d_out;
    float* out_zm2 = out_zm1 + (size_t)N_NODES * 256;
    float* out_hm  = out_zm2 + (size_t)N_NODES * 256;

    // ---- workspace carve (~61.2 MB) ----
    char* w = (char*)d_ws;
    unsigned short* PAb   = (unsigned short*)w; w += 25600000;   // Zb2 -> ZM -> part_alpha
    unsigned short* curA  = (unsigned short*)w; w += 25600000;   // Zb1 -> ZM ping
    int* sdst             = (int*)w;            w += 3200000;
    float* sval           = (float*)w;          w += 3200000;
    int* counts           = (int*)w;            w += 200192;
    int* rowptr           = (int*)w;            w += 200192;
    int* cursor           = (int*)w;            w += 200192;
    float* G1             = (float*)w;          w += 262144;
    float* G2             = (float*)w;          w += 262144;
    float* E1             = (float*)w;          w += 262144;
    float* E2             = (float*)w;          w += 262144;
    float* SMh            = (float*)w;          w += 262144;
    float* S              = (float*)w;          w += 262144;
    float* P2             = (float*)w;          w += 262144;
    float* P3             = (float*)w;          w += 262144;
    float* rs             = (float*)w;          w += 2048;
    float* cs             = (float*)w;          w += 2048;
    float* gmax           = (float*)w;          w += 256;
    int* bsum             = (int*)w;            w += 1024;
    int* boff             = (int*)w;            w += 1024;
    unsigned short* Wt1   = (unsigned short*)w; w += 393216;
    unsigned short* Wt2   = (unsigned short*)w; w += 262144;
    unsigned short* St    = (unsigned short*)w; w += 131072;
    size_t ws_need = (size_t)(w - (char*)d_ws);

    unsigned short* curB  = (unsigned short*)out_hm;   // dead until k_hm

    bool sizes_ok = (n_in == 9)
        && in_sizes[0] == 38400000 && in_sizes[1] == 25600000
        && in_sizes[2] == 800000 && in_sizes[3] == 800000 && in_sizes[4] == 800000
        && in_sizes[5] == 196608 && in_sizes[6] == 256
        && in_sizes[7] == 131072 && in_sizes[8] == 256;
    float c0 = (n_in != 9) ? 1000.f : 0.f;
    float c1 = (!sizes_ok && n_in == 9) ? 2000.f : 0.f;
    float c2 = (ws_size < ws_need) ? (4000.f + (float)(ws_size / 1000000ull)) : 0.f;

    // 0) weights -> bf16 transposed
    k_wt<<<768, 256, 0, stream>>>(W1, Wt1, 768);
    k_wt<<<512, 256, 0, stream>>>(W2, Wt2, 512);

    // 1) ZM1/ZM2 via MFMA 128-row tiles (prefetch-pipelined), dual fp32+bf16 store
    k_gemm_mfma<<<(N_NODES + 127) / 128, 512, 0, stream>>>(X1, Wt1, b1, out_zm1, curA, N_NODES, 768);
    k_gemm_mfma<<<(N_NODES + 127) / 128, 512, 0, stream>>>(X2, Wt2, b2, out_zm2, PAb, N_NODES, 512);

    // 2) Grams + fused/batched softmax chain
    hipMemsetAsync(G1, 0, 262144, stream);
    hipMemsetAsync(G2, 0, 262144, stream);
    hipMemsetAsync(cs, 0, 2048, stream);
    k_gram_mfma<<<dim3(2, 49, 2), 512, 0, stream>>>(curA, PAb, G1, G2, N_NODES);
    k_max2<<<2, 256, 0, stream>>>(G1, G2, gmax);
    k_exprow<<<dim3(256, 2), 256, 0, stream>>>(G1, G2, gmax, E1, E2, rs);
    k_colsum<<<dim3(8, 2), 256, 0, stream>>>(E1, E2, cs);
    k_smacc<<<256, 256, 0, stream>>>(E1, E2, rs, cs, SMh);

    // 3) ZM: in-place average of Zb1 (curA) and Zb2 (PAb)
    k_zm<<<6250, 256, 0, stream>>>(curA, PAb);

    // 4) CSR by src (parallel 3-phase scan)
    hipMemsetAsync(counts, 0, 200192, stream);
    k_hist<<<NE / 256, 256, 0, stream>>>(esrc, counts);
    k_bsum<<<NBLK_SCAN, 256, 0, stream>>>(counts, bsum);
    k_bscan<<<1, 256, 0, stream>>>(bsum, boff, rowptr);
    k_rowptr<<<NBLK_SCAN, 256, 0, stream>>>(counts, boff, rowptr, cursor);
    k_scatter<<<NE / 256, 256, 0, stream>>>(esrc, edst, eval, cursor, sdst, sval);

    // 5) 4 propagation layers (curB parked in out_hm region)
    k_spmm<<<N_NODES, 256, 0, stream>>>(rowptr, sdst, sval, curA, curB, PAb);
    k_spmm<<<N_NODES, 256, 0, stream>>>(rowptr, sdst, sval, curB, curA, PAb);
    k_spmm<<<N_NODES, 256, 0, stream>>>(rowptr, sdst, sval, curA, curB, PAb);
    k_spmm<<<N_NODES, 256, 0, stream>>>(rowptr, sdst, sval, curB, curA, PAb);

    // 6) S = I + B + B^2 + B^3, then St = bf16(S^T)
    k_sinit<<<256, 256, 0, stream>>>(SMh, S);
    k_sgemm<<<256, 256, 0, stream>>>(SMh, SMh, P2, S);
    k_sgemm<<<256, 256, 0, stream>>>(P2, SMh, P3, S);
    k_st<<<256, 256, 0, stream>>>(S, St);

    // 7) HM = l2norm(PA @ S) via MFMA 128-row tiles (prefetch-pipelined)
    k_hm_mfma<<<(N_NODES + 127) / 128, 512, 0, stream>>>(PAb, St, out_hm, N_NODES);

    // 8) diagnostic stamps
    k_stamp<<<1, 1, 0, stream>>>(out_zm1, c0, c1, c2);
}